// Round 3
// baseline (2451.723 us; speedup 1.0000x reference)
//
#include <hip/hip_runtime.h>

// ---------- bf16 helpers (raw ushort representation) ----------
__device__ __forceinline__ float b2f(unsigned int u16) {
    union { unsigned int i; float f; } v;
    v.i = u16 << 16;
    return v.f;
}
__device__ __forceinline__ unsigned short f2b(float f) {
    unsigned int i = __float_as_uint(f);
    unsigned int r = (i + 0x7FFFu + ((i >> 16) & 1u)) >> 16;  // round-nearest-even
    return (unsigned short)r;
}

// ---------- sizes ----------
#define N_WORD  50000
#define N_TOPIC 2000
#define N_DOC   50000
// D_WORD=256, D_TOPIC=128, D_OUT=128

// ---------------------------------------------------------------
// Input-dtype detection. Reads 256 uint32 of feat_word; if the data is
// packed bf16 (N(0,1) features), the LOW ushort of each uint32 is a bf16
// with exponent in [110,140] (~always). If the data is f32, those 16 bits
// are uniform mantissa bits -> exponent field uniform -> ~12% hit rate.
// flag = 1 -> bf16 inputs, 0 -> f32 inputs.
// ---------------------------------------------------------------
__global__ void detect_kernel(const unsigned int* __restrict__ feat_u32,
                              unsigned int* __restrict__ flag)
{
    int cnt = 0;
    for (int i = 0; i < 256; ++i) {
        unsigned int u = feat_u32[i];
        int e = (u >> 7) & 0xFF;   // low ushort viewed as bf16: exponent
        if (e >= 110 && e <= 140) ++cnt;
    }
    *flag = (cnt > 128) ? 1u : 0u;
}

// ---------------------------------------------------------------
// Generic projection: O = feat @ W + b  (f32 accum, bf16 out)
// feat [nrows, K], W [K,128], b [128]; dtype of the three picked by flag.
// 128 threads (one output column each), 8 rows/block; nrows % 8 == 0.
// ---------------------------------------------------------------
template <int K>
__global__ __launch_bounds__(128) void gemm_kernel(
    const void* __restrict__ feat_,
    const void* __restrict__ W_,
    const void* __restrict__ bias_,
    unsigned short* __restrict__ O,
    const unsigned int* __restrict__ flag_p)
{
    const int t = threadIdx.x;          // output column 0..127
    const int row0 = blockIdx.x * 8;
    const int mode_bf16 = (int)*flag_p; // wave-uniform
    __shared__ float fs[8][K];

    if (mode_bf16) {
        const unsigned short* feat = (const unsigned short*)feat_;
#pragma unroll
        for (int r = 0; r < 8; ++r) {
            if (K == 256 || t < K / 2) {
                unsigned int u = ((const unsigned int*)(feat + (size_t)(row0 + r) * K))[t];
                fs[r][2 * t]     = b2f(u & 0xffffu);
                fs[r][2 * t + 1] = b2f(u >> 16);
            }
        }
    } else {
        const float* feat = (const float*)feat_;
#pragma unroll
        for (int r = 0; r < 8; ++r) {
            const float* ff = feat + (size_t)(row0 + r) * K;
            for (int j = t; j < K; j += 128) fs[r][j] = ff[j];
        }
    }
    __syncthreads();

    float acc[8] = {0, 0, 0, 0, 0, 0, 0, 0};

    if (mode_bf16) {
        const unsigned short* W = (const unsigned short*)W_;
        for (int k4 = 0; k4 < K / 4; ++k4) {
            float w[4];
#pragma unroll
            for (int j = 0; j < 4; ++j)
                w[j] = b2f((unsigned int)W[(k4 * 4 + j) * 128 + t]);
#pragma unroll
            for (int r = 0; r < 8; ++r) {
                float4 f = ((const float4*)fs[r])[k4];
                acc[r] += f.x * w[0] + f.y * w[1] + f.z * w[2] + f.w * w[3];
            }
        }
    } else {
        const float* W = (const float*)W_;
        for (int k4 = 0; k4 < K / 4; ++k4) {
            float w[4];
#pragma unroll
            for (int j = 0; j < 4; ++j)
                w[j] = W[(k4 * 4 + j) * 128 + t];
#pragma unroll
            for (int r = 0; r < 8; ++r) {
                float4 f = ((const float4*)fs[r])[k4];
                acc[r] += f.x * w[0] + f.y * w[1] + f.z * w[2] + f.w * w[3];
            }
        }
    }

    const float bb = mode_bf16 ? b2f((unsigned int)((const unsigned short*)bias_)[t])
                               : ((const float*)bias_)[t];
#pragma unroll
    for (int r = 0; r < 8; ++r)
        O[(size_t)(row0 + r) * 128 + t] = f2b(acc[r] + bb);
}

// ---------------------------------------------------------------
// Degree count: deg[dst[e]] += 1.0   (int indices, dtype-independent)
// ---------------------------------------------------------------
__global__ void degree_kernel(const int* __restrict__ dst, int nE,
                              float* __restrict__ deg)
{
    int i = blockIdx.x * blockDim.x + threadIdx.x;
    if (i < nE) atomicAdd(&deg[dst[i]], 1.0f);
}

// ---------------------------------------------------------------
// Scatter: one wave (64 lanes) per edge, 2 dims per lane.
// s[dst] += Wh[src] * (w / deg[dst]); accumulator ends up normalized,
// so cross-etype sum is plain addition into the same buffer.
// Wh is always bf16 (we produced it).
// ---------------------------------------------------------------
__global__ __launch_bounds__(256) void scatter_kernel(
    const int* __restrict__ src, const int* __restrict__ dst,
    const void* __restrict__ w_,
    const unsigned short* __restrict__ Wh,   // [n_src, 128] bf16
    const float* __restrict__ deg,
    float* __restrict__ s,                   // [n_dst, 128] f32
    int nE,
    const unsigned int* __restrict__ flag_p)
{
    const int wid = (blockIdx.x * 256 + threadIdx.x) >> 6;   // edge id
    const int lane = threadIdx.x & 63;
    if (wid >= nE) return;

    const int sidx = src[wid];
    const int didx = dst[wid];
    const float wv = (*flag_p) ? b2f((unsigned int)((const unsigned short*)w_)[wid])
                               : ((const float*)w_)[wid];
    const float d = deg[didx];
    const float scale = (d > 0.0f) ? wv / d : 0.0f;

    const unsigned int u = ((const unsigned int*)(Wh + (size_t)sidx * 128))[lane];
    const float v0 = b2f(u & 0xffffu) * scale;
    const float v1 = b2f(u >> 16) * scale;

    float* sp = s + (size_t)didx * 128 + 2 * lane;
    atomicAdd(sp,     v0);
    atomicAdd(sp + 1, v1);
}

// ---------------------------------------------------------------
// Finalize: f32 accumulators (already in output order) -> out,
// as bf16 (mode 1) or f32 (mode 0).
// ---------------------------------------------------------------
__global__ void finalize_kernel(const float* __restrict__ s,
                                void* __restrict__ out,
                                const unsigned int* __restrict__ flag_p)
{
    const int i = blockIdx.x * blockDim.x + threadIdx.x;
    float4 v = ((const float4*)s)[i];
    if (*flag_p) {
        ushort4 o;
        o.x = f2b(v.x); o.y = f2b(v.y); o.z = f2b(v.z); o.w = f2b(v.w);
        ((ushort4*)out)[i] = o;
    } else {
        ((float4*)out)[i] = v;
    }
}

// ---------------------------------------------------------------
extern "C" void kernel_launch(void* const* d_in, const int* in_sizes, int n_in,
                              void* d_out, int out_size, void* d_ws, size_t ws_size,
                              hipStream_t stream)
{
    const void* feat_word  = d_in[0];
    const void* feat_topic = d_in[1];
    const int* ww_src = (const int*)d_in[2];
    const int* ww_dst = (const int*)d_in[3];
    const void* ww_w = d_in[4];
    const int* wt_src = (const int*)d_in[5];
    const int* wt_dst = (const int*)d_in[6];
    const void* wt_w = d_in[7];
    const int* wd_src = (const int*)d_in[8];
    const int* wd_dst = (const int*)d_in[9];
    const void* wd_w = d_in[10];
    const int* td_src = (const int*)d_in[11];
    const int* td_dst = (const int*)d_in[12];
    const void* td_w = d_in[13];
    const int* tt_src = (const int*)d_in[14];
    const int* tt_dst = (const int*)d_in[15];
    const void* tt_w = d_in[16];
    const void* W_ww = d_in[17];
    const void* b_ww = d_in[18];
    const void* W_wt = d_in[19];
    const void* b_wt = d_in[20];
    const void* W_wd = d_in[21];
    const void* b_wd = d_in[22];
    const void* W_td = d_in[23];
    const void* b_td = d_in[24];
    const void* W_tt = d_in[25];
    const void* b_tt = d_in[26];

    const int E_ww = in_sizes[2];
    const int E_wt = in_sizes[5];
    const int E_wd = in_sizes[8];
    const int E_td = in_sizes[11];
    const int E_tt = in_sizes[14];

    // ---------------- workspace layout (floats) ----------------
    // 52.84 MB of d_ws:
    // [0 .. 13,056,000)           : s_word | s_topic | s_doc (== output order)
    // [13,056,000 .. 13,210,000)  : degree arrays
    // [13,210,000]                : dtype flag (uint32)
    float* fws = (float*)d_ws;
    float* s_word  = fws;                 // 50000*128 = 6,400,000
    float* s_topic = fws + 6400000;       //  2000*128 =   256,000
    float* s_doc   = fws + 6656000;       // 50000*128 = 6,400,000
    float* deg_ww  = fws + 13056000;      // 50,000
    float* deg_wt  = fws + 13106000;      //  2,000
    float* deg_tt  = fws + 13108000;      //  2,000
    float* deg_wd  = fws + 13110000;      // 50,000
    float* deg_td  = fws + 13160000;      // 50,000
    const size_t zero_floats = 13210000;  // must start at 0
    unsigned int* flag = (unsigned int*)(fws + zero_floats);

    // Wh staging lives in d_out (>= 25.6 MB in either dtype mode), reused
    // sequentially; finalize overwrites d_out at the very end.
    unsigned short* slot0 = (unsigned short*)d_out;             // 6,400,000 bf16
    unsigned short* slot1 = (unsigned short*)d_out + 6400000;   // 6,400,000 bf16

    detect_kernel<<<1, 1, 0, stream>>>((const unsigned int*)feat_word, flag);
    hipMemsetAsync(d_ws, 0, zero_floats * sizeof(float), stream);

    // degrees (independent of projections)
    degree_kernel<<<(E_ww + 255) / 256, 256, 0, stream>>>(ww_dst, E_ww, deg_ww);
    degree_kernel<<<(E_wt + 255) / 256, 256, 0, stream>>>(wt_dst, E_wt, deg_wt);
    degree_kernel<<<(E_tt + 255) / 256, 256, 0, stream>>>(tt_dst, E_tt, deg_tt);
    degree_kernel<<<(E_wd + 255) / 256, 256, 0, stream>>>(wd_dst, E_wd, deg_wd);
    degree_kernel<<<(E_td + 255) / 256, 256, 0, stream>>>(td_dst, E_td, deg_td);

    // relation ww: project into slot0, wd into slot1, then scatter both
    gemm_kernel<256><<<N_WORD / 8, 128, 0, stream>>>(feat_word, W_ww, b_ww, slot0, flag);
    gemm_kernel<256><<<N_WORD / 8, 128, 0, stream>>>(feat_word, W_wd, b_wd, slot1, flag);
    scatter_kernel<<<(E_ww + 3) / 4, 256, 0, stream>>>(ww_src, ww_dst, ww_w, slot0, deg_ww, s_word, E_ww, flag);
    scatter_kernel<<<(E_wd + 3) / 4, 256, 0, stream>>>(wd_src, wd_dst, wd_w, slot1, deg_wd, s_doc, E_wd, flag);

    // relation wt: reuse slot0 (stream order: scatter ww already done)
    gemm_kernel<256><<<N_WORD / 8, 128, 0, stream>>>(feat_word, W_wt, b_wt, slot0, flag);
    scatter_kernel<<<(E_wt + 3) / 4, 256, 0, stream>>>(wt_src, wt_dst, wt_w, slot0, deg_wt, s_topic, E_wt, flag);

    // relation td: reuse slot1
    gemm_kernel<128><<<N_TOPIC / 8, 128, 0, stream>>>(feat_topic, W_td, b_td, slot1, flag);
    scatter_kernel<<<(E_td + 3) / 4, 256, 0, stream>>>(td_src, td_dst, td_w, slot1, deg_td, s_doc, E_td, flag);

    // relation tt: reuse slot0
    gemm_kernel<128><<<N_TOPIC / 8, 128, 0, stream>>>(feat_topic, W_tt, b_tt, slot0, flag);
    scatter_kernel<<<(E_tt + 3) / 4, 256, 0, stream>>>(tt_src, tt_dst, tt_w, slot0, deg_tt, s_topic, E_tt, flag);

    // convert accumulators (already in output order) -> d_out; overwrites
    // the staging slots — all scatters are done by now.
    finalize_kernel<<<(out_size / 4 + 255) / 256, 256, 0, stream>>>(fws, d_out, flag);
}

// Round 4
// 1201.788 us; speedup vs baseline: 2.0401x; 2.0401x over previous
//
#include <hip/hip_runtime.h>

// ---------- bf16 helpers (raw ushort representation) ----------
__device__ __forceinline__ float b2f(unsigned int u16) {
    union { unsigned int i; float f; } v;
    v.i = u16 << 16;
    return v.f;
}
__device__ __forceinline__ unsigned short f2b(float f) {
    unsigned int i = __float_as_uint(f);
    unsigned int r = (i + 0x7FFFu + ((i >> 16) & 1u)) >> 16;  // round-nearest-even
    return (unsigned short)r;
}

// ---------- sizes ----------
#define N_WORD  50000
#define N_TOPIC 2000
#define N_DOC   50000
#define E_MAX   500000
// D_WORD=256, D_TOPIC=128, D_OUT=128

// ---------------------------------------------------------------
// Input-dtype detection (see round 3): flag=1 -> bf16 inputs, 0 -> f32.
// ---------------------------------------------------------------
__global__ void detect_kernel(const unsigned int* __restrict__ feat_u32,
                              unsigned int* __restrict__ flag)
{
    int cnt = 0;
    for (int i = 0; i < 256; ++i) {
        unsigned int u = feat_u32[i];
        int e = (u >> 7) & 0xFF;   // low ushort viewed as bf16: exponent
        if (e >= 110 && e <= 140) ++cnt;
    }
    *flag = (cnt > 128) ? 1u : 0u;
}

// ---------------------------------------------------------------
// Projection: O = feat @ W + b (f32 accum, bf16 out). Unchanged from R3.
// ---------------------------------------------------------------
template <int K>
__global__ __launch_bounds__(128) void gemm_kernel(
    const void* __restrict__ feat_,
    const void* __restrict__ W_,
    const void* __restrict__ bias_,
    unsigned short* __restrict__ O,
    const unsigned int* __restrict__ flag_p)
{
    const int t = threadIdx.x;          // output column 0..127
    const int row0 = blockIdx.x * 8;
    const int mode_bf16 = (int)*flag_p; // wave-uniform
    __shared__ float fs[8][K];

    if (mode_bf16) {
        const unsigned short* feat = (const unsigned short*)feat_;
#pragma unroll
        for (int r = 0; r < 8; ++r) {
            if (K == 256 || t < K / 2) {
                unsigned int u = ((const unsigned int*)(feat + (size_t)(row0 + r) * K))[t];
                fs[r][2 * t]     = b2f(u & 0xffffu);
                fs[r][2 * t + 1] = b2f(u >> 16);
            }
        }
    } else {
        const float* feat = (const float*)feat_;
#pragma unroll
        for (int r = 0; r < 8; ++r) {
            const float* ff = feat + (size_t)(row0 + r) * K;
            for (int j = t; j < K; j += 128) fs[r][j] = ff[j];
        }
    }
    __syncthreads();

    float acc[8] = {0, 0, 0, 0, 0, 0, 0, 0};

    if (mode_bf16) {
        const unsigned short* W = (const unsigned short*)W_;
        for (int k4 = 0; k4 < K / 4; ++k4) {
            float w[4];
#pragma unroll
            for (int j = 0; j < 4; ++j)
                w[j] = b2f((unsigned int)W[(k4 * 4 + j) * 128 + t]);
#pragma unroll
            for (int r = 0; r < 8; ++r) {
                float4 f = ((const float4*)fs[r])[k4];
                acc[r] += f.x * w[0] + f.y * w[1] + f.z * w[2] + f.w * w[3];
            }
        }
    } else {
        const float* W = (const float*)W_;
        for (int k4 = 0; k4 < K / 4; ++k4) {
            float w[4];
#pragma unroll
            for (int j = 0; j < 4; ++j)
                w[j] = W[(k4 * 4 + j) * 128 + t];
#pragma unroll
            for (int r = 0; r < 8; ++r) {
                float4 f = ((const float4*)fs[r])[k4];
                acc[r] += f.x * w[0] + f.y * w[1] + f.z * w[2] + f.w * w[3];
            }
        }
    }

    const float bb = mode_bf16 ? b2f((unsigned int)((const unsigned short*)bias_)[t])
                               : ((const float*)bias_)[t];
#pragma unroll
    for (int r = 0; r < 8; ++r)
        O[(size_t)(row0 + r) * 128 + t] = f2b(acc[r] + bb);
}

// ---------------------------------------------------------------
// CSR build step 1: histogram of destination indices (int atomics).
// ---------------------------------------------------------------
__global__ void hist_kernel(const int* __restrict__ dst, int nE,
                            int* __restrict__ cnt)
{
    int i = blockIdx.x * blockDim.x + threadIdx.x;
    if (i < nE) atomicAdd(&cnt[dst[i]], 1);
}

// ---------------------------------------------------------------
// CSR build step 2: exclusive scan cnt[0..n) -> row_ptr[0..n].
// One 1024-thread block; chunked + LDS Hillis-Steele over chunk sums.
// ---------------------------------------------------------------
__global__ __launch_bounds__(1024) void scan_kernel(
    const int* __restrict__ cnt, int* __restrict__ row_ptr, int n)
{
    __shared__ int sums[1024];
    const int t = threadIdx.x;
    const int chunk = (n + 1023) / 1024;
    int start = t * chunk; if (start > n) start = n;
    int end = start + chunk; if (end > n) end = n;

    int s = 0;
    for (int i = start; i < end; ++i) s += cnt[i];
    sums[t] = s;
    __syncthreads();
    for (int off = 1; off < 1024; off <<= 1) {
        int v = (t >= off) ? sums[t - off] : 0;
        __syncthreads();
        sums[t] += v;
        __syncthreads();
    }
    int run = (t == 0) ? 0 : sums[t - 1];   // exclusive prefix of my chunk
    for (int i = start; i < end; ++i) { row_ptr[i] = run; run += cnt[i]; }
    if (end == n) row_ptr[n] = run;         // total (benign multi-write, same value)
}

// ---------------------------------------------------------------
// CSR build step 3: place (src, w_f32) pairs at row_ptr[dst] + cursor++.
// ---------------------------------------------------------------
__global__ void build_kernel(const int* __restrict__ src,
                             const int* __restrict__ dst,
                             const void* __restrict__ w_,
                             int nE,
                             const int* __restrict__ row_ptr,
                             int* __restrict__ cursor,
                             int2* __restrict__ pairs,
                             const unsigned int* __restrict__ flag_p)
{
    int i = blockIdx.x * blockDim.x + threadIdx.x;
    if (i >= nE) return;
    int d = dst[i];
    int pos = row_ptr[d] + atomicAdd(&cursor[d], 1);
    float wv = (*flag_p) ? b2f((unsigned int)((const unsigned short*)w_)[i])
                         : ((const float*)w_)[i];
    pairs[pos] = make_int2(src[i], __float_as_int(wv));
}

// ---------------------------------------------------------------
// Gather, 1 relation: out[node] = mean_e(Wh[src_e] * w_e).
// One wave (64 lanes) per dst node, 2 dims/lane; writes d_out directly.
// ---------------------------------------------------------------
__global__ __launch_bounds__(256) void gather1_kernel(
    const int* __restrict__ row_ptr, const int2* __restrict__ pairs,
    const unsigned short* __restrict__ Wh,
    void* __restrict__ out, int n_dst, size_t out_off,
    const unsigned int* __restrict__ flag_p)
{
    const int node = (blockIdx.x * 256 + threadIdx.x) >> 6;
    const int lane = threadIdx.x & 63;
    if (node >= n_dst) return;

    const int beg = row_ptr[node], end = row_ptr[node + 1];
    float a0 = 0.0f, a1 = 0.0f;
    int e = beg;
    for (; e + 1 < end; e += 2) {                 // 2-way unroll for MLP
        int2 p0 = pairs[e], p1 = pairs[e + 1];
        unsigned int u0 = ((const unsigned int*)(Wh + (size_t)p0.x * 128))[lane];
        unsigned int u1 = ((const unsigned int*)(Wh + (size_t)p1.x * 128))[lane];
        float w0 = __int_as_float(p0.y), w1 = __int_as_float(p1.y);
        a0 += b2f(u0 & 0xffffu) * w0 + b2f(u1 & 0xffffu) * w1;
        a1 += b2f(u0 >> 16) * w0 + b2f(u1 >> 16) * w1;
    }
    if (e < end) {
        int2 p = pairs[e];
        unsigned int u = ((const unsigned int*)(Wh + (size_t)p.x * 128))[lane];
        float wv = __int_as_float(p.y);
        a0 += b2f(u & 0xffffu) * wv;
        a1 += b2f(u >> 16) * wv;
    }
    const float inv = (end > beg) ? 1.0f / (float)(end - beg) : 0.0f;
    a0 *= inv; a1 *= inv;

    const size_t o = out_off + (size_t)node * 128 + 2 * lane;
    if (*flag_p) {
        ushort2 s; s.x = f2b(a0); s.y = f2b(a1);
        *(ushort2*)((unsigned short*)out + o) = s;
    } else {
        *(float2*)((float*)out + o) = make_float2(a0, a1);
    }
}

// ---------------------------------------------------------------
// Gather, 2 relations summed: out[node] = meanA(node) + meanB(node).
// ---------------------------------------------------------------
__global__ __launch_bounds__(256) void gather2_kernel(
    const int* __restrict__ row_ptrA, const int2* __restrict__ pairsA,
    const unsigned short* __restrict__ WhA,
    const int* __restrict__ row_ptrB, const int2* __restrict__ pairsB,
    const unsigned short* __restrict__ WhB,
    void* __restrict__ out, int n_dst, size_t out_off,
    const unsigned int* __restrict__ flag_p)
{
    const int node = (blockIdx.x * 256 + threadIdx.x) >> 6;
    const int lane = threadIdx.x & 63;
    if (node >= n_dst) return;

    float r0 = 0.0f, r1 = 0.0f;

#pragma unroll
    for (int rel = 0; rel < 2; ++rel) {
        const int* rp = rel ? row_ptrB : row_ptrA;
        const int2* pr = rel ? pairsB : pairsA;
        const unsigned short* Wh = rel ? WhB : WhA;
        const int beg = rp[node], end = rp[node + 1];
        float a0 = 0.0f, a1 = 0.0f;
        int e = beg;
        for (; e + 1 < end; e += 2) {
            int2 p0 = pr[e], p1 = pr[e + 1];
            unsigned int u0 = ((const unsigned int*)(Wh + (size_t)p0.x * 128))[lane];
            unsigned int u1 = ((const unsigned int*)(Wh + (size_t)p1.x * 128))[lane];
            float w0 = __int_as_float(p0.y), w1 = __int_as_float(p1.y);
            a0 += b2f(u0 & 0xffffu) * w0 + b2f(u1 & 0xffffu) * w1;
            a1 += b2f(u0 >> 16) * w0 + b2f(u1 >> 16) * w1;
        }
        if (e < end) {
            int2 p = pr[e];
            unsigned int u = ((const unsigned int*)(Wh + (size_t)p.x * 128))[lane];
            float wv = __int_as_float(p.y);
            a0 += b2f(u & 0xffffu) * wv;
            a1 += b2f(u >> 16) * wv;
        }
        const float inv = (end > beg) ? 1.0f / (float)(end - beg) : 0.0f;
        r0 += a0 * inv; r1 += a1 * inv;
    }

    const size_t o = out_off + (size_t)node * 128 + 2 * lane;
    if (*flag_p) {
        ushort2 s; s.x = f2b(r0); s.y = f2b(r1);
        *(ushort2*)((unsigned short*)out + o) = s;
    } else {
        *(float2*)((float*)out + o) = make_float2(r0, r1);
    }
}

// ---------------------------------------------------------------
extern "C" void kernel_launch(void* const* d_in, const int* in_sizes, int n_in,
                              void* d_out, int out_size, void* d_ws, size_t ws_size,
                              hipStream_t stream)
{
    const void* feat_word  = d_in[0];
    const void* feat_topic = d_in[1];
    const int* ww_src = (const int*)d_in[2];
    const int* ww_dst = (const int*)d_in[3];
    const void* ww_w = d_in[4];
    const int* wt_src = (const int*)d_in[5];
    const int* wt_dst = (const int*)d_in[6];
    const void* wt_w = d_in[7];
    const int* wd_src = (const int*)d_in[8];
    const int* wd_dst = (const int*)d_in[9];
    const void* wd_w = d_in[10];
    const int* td_src = (const int*)d_in[11];
    const int* td_dst = (const int*)d_in[12];
    const void* td_w = d_in[13];
    const int* tt_src = (const int*)d_in[14];
    const int* tt_dst = (const int*)d_in[15];
    const void* tt_w = d_in[16];
    const void* W_ww = d_in[17];
    const void* b_ww = d_in[18];
    const void* W_wt = d_in[19];
    const void* b_wt = d_in[20];
    const void* W_wd = d_in[21];
    const void* b_wd = d_in[22];
    const void* W_td = d_in[23];
    const void* b_td = d_in[24];
    const void* W_tt = d_in[25];
    const void* b_tt = d_in[26];

    const int E_ww = in_sizes[2];
    const int E_wt = in_sizes[5];
    const int E_wd = in_sizes[8];
    const int E_td = in_sizes[11];
    const int E_tt = in_sizes[14];

    // ---------------- workspace layout (~35 MB) ----------------
    // ints first: flag | cnt[154000] | cursor[154000] | row_ptr[154005]
    // then Wh slots (bf16), then pairs (int2).
    int* iws = (int*)d_ws;
    unsigned int* flag = (unsigned int*)iws;          // 1
    int* cnt_base    = iws + 1;                       // 154,000
    int* cnt_ww = cnt_base;                           // 50,000
    int* cnt_wt = cnt_ww + 50000;                     //  2,000
    int* cnt_tt = cnt_wt + 2000;                      //  2,000
    int* cnt_wd = cnt_tt + 2000;                      // 50,000
    int* cnt_td = cnt_wd + 50000;                     // 50,000
    int* cur_base    = cnt_base + 154000;             // 154,000
    int* cur_ww = cur_base;
    int* cur_wt = cur_ww + 50000;
    int* cur_tt = cur_wt + 2000;
    int* cur_wd = cur_tt + 2000;
    int* cur_td = cur_wd + 50000;
    int* rp_base     = cur_base + 154000;             // 154,005
    int* rp_ww = rp_base;                             // 50,001
    int* rp_wt = rp_ww + 50001;                       //  2,001
    int* rp_tt = rp_wt + 2001;                        //  2,001
    int* rp_wd = rp_tt + 2001;                        // 50,001
    int* rp_td = rp_wd + 50001;                       // 50,001

    // Wh slots (bf16): slotA word-sized (reused 3x), slotB topic-sized (2x)
    unsigned short* slotA = (unsigned short*)(rp_base + 154005 + 1 /*align pad*/);
    // align slotA to 4 bytes is inherent; give pairs 8B alignment below
    unsigned short* slotB = slotA + (size_t)N_WORD * 128;        // 6,400,000 + 256,000
    size_t pair_off_bytes = ((size_t)(slotB + (size_t)N_TOPIC * 128) - (size_t)d_ws + 7) & ~(size_t)7;
    int2* pairs_ww = (int2*)((char*)d_ws + pair_off_bytes);      // E_MAX each
    int2* pairs_wt = pairs_ww + E_MAX;
    int2* pairs_tt = pairs_wt + E_MAX;
    int2* pairs_wd = pairs_tt + E_MAX;
    int2* pairs_td = pairs_wd + E_MAX;

    // dtype detect + zero flag-adjacent int region (cnt + cursor)
    detect_kernel<<<1, 1, 0, stream>>>((const unsigned int*)feat_word, flag);
    hipMemsetAsync(cnt_base, 0, (154000 + 154000) * sizeof(int), stream);

    // CSR: histograms
    hist_kernel<<<(E_ww + 255) / 256, 256, 0, stream>>>(ww_dst, E_ww, cnt_ww);
    hist_kernel<<<(E_wt + 255) / 256, 256, 0, stream>>>(wt_dst, E_wt, cnt_wt);
    hist_kernel<<<(E_tt + 255) / 256, 256, 0, stream>>>(tt_dst, E_tt, cnt_tt);
    hist_kernel<<<(E_wd + 255) / 256, 256, 0, stream>>>(wd_dst, E_wd, cnt_wd);
    hist_kernel<<<(E_td + 255) / 256, 256, 0, stream>>>(td_dst, E_td, cnt_td);

    // CSR: scans
    scan_kernel<<<1, 1024, 0, stream>>>(cnt_ww, rp_ww, N_WORD);
    scan_kernel<<<1, 1024, 0, stream>>>(cnt_wt, rp_wt, N_TOPIC);
    scan_kernel<<<1, 1024, 0, stream>>>(cnt_tt, rp_tt, N_TOPIC);
    scan_kernel<<<1, 1024, 0, stream>>>(cnt_wd, rp_wd, N_DOC);
    scan_kernel<<<1, 1024, 0, stream>>>(cnt_td, rp_td, N_DOC);

    // CSR: place pairs
    build_kernel<<<(E_ww + 255) / 256, 256, 0, stream>>>(ww_src, ww_dst, ww_w, E_ww, rp_ww, cur_ww, pairs_ww, flag);
    build_kernel<<<(E_wt + 255) / 256, 256, 0, stream>>>(wt_src, wt_dst, wt_w, E_wt, rp_wt, cur_wt, pairs_wt, flag);
    build_kernel<<<(E_tt + 255) / 256, 256, 0, stream>>>(tt_src, tt_dst, tt_w, E_tt, rp_tt, cur_tt, pairs_tt, flag);
    build_kernel<<<(E_wd + 255) / 256, 256, 0, stream>>>(wd_src, wd_dst, wd_w, E_wd, rp_wd, cur_wd, pairs_wd, flag);
    build_kernel<<<(E_td + 255) / 256, 256, 0, stream>>>(td_src, td_dst, td_w, E_td, rp_td, cur_td, pairs_td, flag);

    // h_word = mean_ww
    gemm_kernel<256><<<N_WORD / 8, 128, 0, stream>>>(feat_word, W_ww, b_ww, slotA, flag);
    gather1_kernel<<<(N_WORD + 3) / 4, 256, 0, stream>>>(rp_ww, pairs_ww, slotA, d_out, N_WORD, 0, flag);

    // h_topic = mean_wt + mean_tt
    gemm_kernel<256><<<N_WORD / 8, 128, 0, stream>>>(feat_word, W_wt, b_wt, slotA, flag);
    gemm_kernel<128><<<N_TOPIC / 8, 128, 0, stream>>>(feat_topic, W_tt, b_tt, slotB, flag);
    gather2_kernel<<<(N_TOPIC + 3) / 4, 256, 0, stream>>>(rp_wt, pairs_wt, slotA,
                                                          rp_tt, pairs_tt, slotB,
                                                          d_out, N_TOPIC, (size_t)6400000, flag);

    // h_doc = mean_wd + mean_td
    gemm_kernel<256><<<N_WORD / 8, 128, 0, stream>>>(feat_word, W_wd, b_wd, slotA, flag);
    gemm_kernel<128><<<N_TOPIC / 8, 128, 0, stream>>>(feat_topic, W_td, b_td, slotB, flag);
    gather2_kernel<<<(N_DOC + 3) / 4, 256, 0, stream>>>(rp_wd, pairs_wd, slotA,
                                                        rp_td, pairs_td, slotB,
                                                        d_out, N_DOC, (size_t)6656000, flag);
}

// Round 5
// 806.346 us; speedup vs baseline: 3.0405x; 1.4904x over previous
//
#include <hip/hip_runtime.h>

typedef short short8 __attribute__((ext_vector_type(8)));
typedef float floatx4 __attribute__((ext_vector_type(4)));

// ---------- bf16 helpers (raw ushort representation) ----------
__device__ __forceinline__ float b2f(unsigned int u16) {
    union { unsigned int i; float f; } v;
    v.i = u16 << 16;
    return v.f;
}
__device__ __forceinline__ unsigned short f2b(float f) {
    unsigned int i = __float_as_uint(f);
    unsigned int r = (i + 0x7FFFu + ((i >> 16) & 1u)) >> 16;  // RNE
    return (unsigned short)r;
}

#define N_WORD  50000
#define N_TOPIC 2000
#define N_DOC   50000
#define E_MAX   500000

// ---------------------------------------------------------------
// Input-dtype detection: flag=1 -> bf16 inputs, 0 -> f32 inputs.
// ---------------------------------------------------------------
__global__ void detect_kernel(const unsigned int* __restrict__ feat_u32,
                              unsigned int* __restrict__ flag)
{
    int cnt = 0;
    for (int i = 0; i < 256; ++i) {
        unsigned int u = feat_u32[i];
        int e = (u >> 7) & 0xFF;   // low ushort viewed as bf16: exponent
        if (e >= 110 && e <= 140) ++cnt;
    }
    *flag = (cnt > 128) ? 1u : 0u;
}

// ---------------------------------------------------------------
// Weight swizzle: W [K,128] (bf16 or f32) -> B-fragment order for
// mfma_f32_16x16x32_bf16: entry(s,t,lane) = 8 bf16 B[k=s*32+q*8+j][n=t*16+(lane&15)],
// stored contiguously so the GEMM does one 16B coalesced load per frag.
// Also canonicalizes the 5 biases to bf16. grid = (8, 5).
// ---------------------------------------------------------------
__global__ __launch_bounds__(256) void swizzle_kernel(
    const void* __restrict__ W0, const void* __restrict__ W1,
    const void* __restrict__ W2, const void* __restrict__ W3,
    const void* __restrict__ W4,
    const void* __restrict__ b0, const void* __restrict__ b1,
    const void* __restrict__ b2, const void* __restrict__ b3,
    const void* __restrict__ b4,
    short8* __restrict__ D0, short8* __restrict__ D1,
    short8* __restrict__ D2, short8* __restrict__ D3,
    short8* __restrict__ D4,
    unsigned short* __restrict__ bias_out,
    const unsigned int* __restrict__ flag_p)
{
    const int w = blockIdx.y;
    const void* W; const void* bs; short8* D; int S;
    switch (w) {
        case 0: W = W0; bs = b0; D = D0; S = 8; break;
        case 1: W = W1; bs = b1; D = D1; S = 8; break;
        case 2: W = W2; bs = b2; D = D2; S = 8; break;
        case 3: W = W3; bs = b3; D = D3; S = 4; break;
        default: W = W4; bs = b4; D = D4; S = 4; break;
    }
    const int n_entries = S * 8 * 64;
    const int mode = (int)*flag_p;
    for (int e = blockIdx.x * 256 + threadIdx.x; e < n_entries; e += 8 * 256) {
        const int lane = e & 63, t = (e >> 6) & 7, s = e >> 9;
        const int q = lane >> 4, n = t * 16 + (lane & 15);
        short8 val;
#pragma unroll
        for (int j = 0; j < 8; ++j) {
            const int k = s * 32 + q * 8 + j;
            unsigned short hv = mode ? ((const unsigned short*)W)[k * 128 + n]
                                     : f2b(((const float*)W)[k * 128 + n]);
            val[j] = (short)hv;
        }
        D[e] = val;
    }
    if (blockIdx.x == 0 && threadIdx.x < 128) {
        bias_out[w * 128 + threadIdx.x] =
            mode ? ((const unsigned short*)bs)[threadIdx.x]
                 : f2b(((const float*)bs)[threadIdx.x]);
    }
}

// ---------------------------------------------------------------
// MFMA GEMM: NP projections of the same A. Wave computes a 16x128 strip.
// A frags loaded once (32 VGPRs for K=256); per phase: 8*S frag loads + MFMAs.
// S = K/32 ksteps. No LDS, no barriers.
// ---------------------------------------------------------------
template <int S, int NP>
__global__ __launch_bounds__(256) void gemm_mfma_kernel(
    const void* __restrict__ feat_, int n_rows,
    const short8* __restrict__ Ba, const short8* __restrict__ Bb,
    const short8* __restrict__ Bc,
    const unsigned short* __restrict__ bias_all, int ba, int bb, int bc,
    unsigned short* __restrict__ Oa, unsigned short* __restrict__ Ob,
    unsigned short* __restrict__ Oc,
    const unsigned int* __restrict__ flag_p)
{
    const int lane = threadIdx.x & 63;
    const int wave = threadIdx.x >> 6;
    const int row0 = (blockIdx.x * 4 + wave) * 16;
    if (row0 >= n_rows) return;
    const int m = lane & 15, q = lane >> 4;
    const int K = S * 32;

    short8 a[S];
    if (*flag_p) {
        const short8* arow = (const short8*)((const unsigned short*)feat_ + (size_t)(row0 + m) * K);
#pragma unroll
        for (int s = 0; s < S; ++s) a[s] = arow[s * 4 + q];
    } else {
        const float* arow = (const float*)feat_ + (size_t)(row0 + m) * K;
#pragma unroll
        for (int s = 0; s < S; ++s) {
            const float4 f0 = ((const float4*)arow)[s * 8 + q * 2];
            const float4 f1 = ((const float4*)arow)[s * 8 + q * 2 + 1];
            short8 t;
            t[0] = (short)f2b(f0.x); t[1] = (short)f2b(f0.y);
            t[2] = (short)f2b(f0.z); t[3] = (short)f2b(f0.w);
            t[4] = (short)f2b(f1.x); t[5] = (short)f2b(f1.y);
            t[6] = (short)f2b(f1.z); t[7] = (short)f2b(f1.w);
            a[s] = t;
        }
    }

#pragma unroll
    for (int p = 0; p < NP; ++p) {
        const short8* B = (p == 0) ? Ba : ((p == 1) ? Bb : Bc);
        const unsigned short* bias = bias_all + ((p == 0) ? ba : ((p == 1) ? bb : bc)) * 128;
        unsigned short* O = (p == 0) ? Oa : ((p == 1) ? Ob : Oc);

        floatx4 acc[8];
#pragma unroll
        for (int t = 0; t < 8; ++t) { acc[t][0] = 0.f; acc[t][1] = 0.f; acc[t][2] = 0.f; acc[t][3] = 0.f; }

#pragma unroll
        for (int s = 0; s < S; ++s) {
#pragma unroll
            for (int t = 0; t < 8; ++t) {
                short8 b = B[(s * 8 + t) * 64 + lane];
                acc[t] = __builtin_amdgcn_mfma_f32_16x16x32_bf16(a[s], b, acc[t], 0, 0, 0);
            }
        }

#pragma unroll
        for (int t = 0; t < 8; ++t) {
            const float bb_ = b2f((unsigned int)bias[t * 16 + m]);
#pragma unroll
            for (int r = 0; r < 4; ++r) {
                const int row = row0 + q * 4 + r;            // C/D: row=quad*4+reg
                O[(size_t)row * 128 + t * 16 + m] = f2b(acc[t][r] + bb_);
            }
        }
    }
}

// ---------------------------------------------------------------
// CSR build, fused over 5 relations (grid.y = relation).
// ---------------------------------------------------------------
__global__ void hist5_kernel(
    const int* d0, int n0, int* c0, const int* d1, int n1, int* c1,
    const int* d2, int n2, int* c2, const int* d3, int n3, int* c3,
    const int* d4, int n4, int* c4)
{
    const int* d; int n; int* c;
    switch (blockIdx.y) {
        case 0: d = d0; n = n0; c = c0; break;
        case 1: d = d1; n = n1; c = c1; break;
        case 2: d = d2; n = n2; c = c2; break;
        case 3: d = d3; n = n3; c = c3; break;
        default: d = d4; n = n4; c = c4; break;
    }
    int i = blockIdx.x * 256 + threadIdx.x;
    if (i < n) atomicAdd(&c[d[i]], 1);
}

__global__ __launch_bounds__(1024) void scan5_kernel(
    const int* c0, int* r0, int n0, const int* c1, int* r1, int n1,
    const int* c2, int* r2, int n2, const int* c3, int* r3, int n3,
    const int* c4, int* r4, int n4)
{
    const int* cnt; int* row_ptr; int n;
    switch (blockIdx.x) {
        case 0: cnt = c0; row_ptr = r0; n = n0; break;
        case 1: cnt = c1; row_ptr = r1; n = n1; break;
        case 2: cnt = c2; row_ptr = r2; n = n2; break;
        case 3: cnt = c3; row_ptr = r3; n = n3; break;
        default: cnt = c4; row_ptr = r4; n = n4; break;
    }
    __shared__ int sums[1024];
    const int t = threadIdx.x;
    const int chunk = (n + 1023) / 1024;
    int start = t * chunk; if (start > n) start = n;
    int end = start + chunk; if (end > n) end = n;

    int s = 0;
    for (int i = start; i < end; ++i) s += cnt[i];
    sums[t] = s;
    __syncthreads();
    for (int off = 1; off < 1024; off <<= 1) {
        int v = (t >= off) ? sums[t - off] : 0;
        __syncthreads();
        sums[t] += v;
        __syncthreads();
    }
    int run = (t == 0) ? 0 : sums[t - 1];
    for (int i = start; i < end; ++i) { row_ptr[i] = run; run += cnt[i]; }
    if (end == n) row_ptr[n] = run;
}

__global__ void build5_kernel(
    const int* s0, const int* d0, const void* w0, int n0, const int* r0, int* u0, int2* p0,
    const int* s1, const int* d1, const void* w1, int n1, const int* r1, int* u1, int2* p1,
    const int* s2, const int* d2, const void* w2, int n2, const int* r2, int* u2, int2* p2,
    const int* s3, const int* d3, const void* w3, int n3, const int* r3, int* u3, int2* p3,
    const int* s4, const int* d4, const void* w4, int n4, const int* r4, int* u4, int2* p4,
    const unsigned int* __restrict__ flag_p)
{
    const int* src; const int* dst; const void* w_; int n;
    const int* rp; int* cur; int2* pairs;
    switch (blockIdx.y) {
        case 0: src = s0; dst = d0; w_ = w0; n = n0; rp = r0; cur = u0; pairs = p0; break;
        case 1: src = s1; dst = d1; w_ = w1; n = n1; rp = r1; cur = u1; pairs = p1; break;
        case 2: src = s2; dst = d2; w_ = w2; n = n2; rp = r2; cur = u2; pairs = p2; break;
        case 3: src = s3; dst = d3; w_ = w3; n = n3; rp = r3; cur = u3; pairs = p3; break;
        default: src = s4; dst = d4; w_ = w4; n = n4; rp = r4; cur = u4; pairs = p4; break;
    }
    int i = blockIdx.x * 256 + threadIdx.x;
    if (i >= n) return;
    int d = dst[i];
    int pos = rp[d] + atomicAdd(&cur[d], 1);
    float wv = (*flag_p) ? b2f((unsigned int)((const unsigned short*)w_)[i])
                         : ((const float*)w_)[i];
    pairs[pos] = make_int2(src[i], __float_as_int(wv));
}

// ---------------------------------------------------------------
// Gather, 1 relation: out[node] = mean_e(Wh[src_e] * w_e).
// One wave per dst node, 2 dims/lane.
// ---------------------------------------------------------------
__global__ __launch_bounds__(256) void gather1_kernel(
    const int* __restrict__ row_ptr, const int2* __restrict__ pairs,
    const unsigned short* __restrict__ Wh,
    void* __restrict__ out, int n_dst, size_t out_off,
    const unsigned int* __restrict__ flag_p)
{
    const int node = (blockIdx.x * 256 + threadIdx.x) >> 6;
    const int lane = threadIdx.x & 63;
    if (node >= n_dst) return;

    const int beg = row_ptr[node], end = row_ptr[node + 1];
    float a0 = 0.0f, a1 = 0.0f;
    int e = beg;
    for (; e + 1 < end; e += 2) {
        int2 p0 = pairs[e], p1 = pairs[e + 1];
        unsigned int u0 = ((const unsigned int*)(Wh + (size_t)p0.x * 128))[lane];
        unsigned int u1 = ((const unsigned int*)(Wh + (size_t)p1.x * 128))[lane];
        float w0 = __int_as_float(p0.y), w1 = __int_as_float(p1.y);
        a0 += b2f(u0 & 0xffffu) * w0 + b2f(u1 & 0xffffu) * w1;
        a1 += b2f(u0 >> 16) * w0 + b2f(u1 >> 16) * w1;
    }
    if (e < end) {
        int2 p = pairs[e];
        unsigned int u = ((const unsigned int*)(Wh + (size_t)p.x * 128))[lane];
        float wv = __int_as_float(p.y);
        a0 += b2f(u & 0xffffu) * wv;
        a1 += b2f(u >> 16) * wv;
    }
    const float inv = (end > beg) ? 1.0f / (float)(end - beg) : 0.0f;
    a0 *= inv; a1 *= inv;

    const size_t o = out_off + (size_t)node * 128 + 2 * lane;
    if (*flag_p) {
        ushort2 s; s.x = f2b(a0); s.y = f2b(a1);
        *(ushort2*)((unsigned short*)out + o) = s;
    } else {
        *(float2*)((float*)out + o) = make_float2(a0, a1);
    }
}

// ---------------------------------------------------------------
// Gather, 2 relations summed.
// ---------------------------------------------------------------
__global__ __launch_bounds__(256) void gather2_kernel(
    const int* __restrict__ row_ptrA, const int2* __restrict__ pairsA,
    const unsigned short* __restrict__ WhA,
    const int* __restrict__ row_ptrB, const int2* __restrict__ pairsB,
    const unsigned short* __restrict__ WhB,
    void* __restrict__ out, int n_dst, size_t out_off,
    const unsigned int* __restrict__ flag_p)
{
    const int node = (blockIdx.x * 256 + threadIdx.x) >> 6;
    const int lane = threadIdx.x & 63;
    if (node >= n_dst) return;

    float r0 = 0.0f, r1 = 0.0f;

#pragma unroll
    for (int rel = 0; rel < 2; ++rel) {
        const int* rp = rel ? row_ptrB : row_ptrA;
        const int2* pr = rel ? pairsB : pairsA;
        const unsigned short* Wh = rel ? WhB : WhA;
        const int beg = rp[node], end = rp[node + 1];
        float a0 = 0.0f, a1 = 0.0f;
        int e = beg;
        for (; e + 1 < end; e += 2) {
            int2 p0 = pr[e], p1 = pr[e + 1];
            unsigned int u0 = ((const unsigned int*)(Wh + (size_t)p0.x * 128))[lane];
            unsigned int u1 = ((const unsigned int*)(Wh + (size_t)p1.x * 128))[lane];
            float w0 = __int_as_float(p0.y), w1 = __int_as_float(p1.y);
            a0 += b2f(u0 & 0xffffu) * w0 + b2f(u1 & 0xffffu) * w1;
            a1 += b2f(u0 >> 16) * w0 + b2f(u1 >> 16) * w1;
        }
        if (e < end) {
            int2 p = pr[e];
            unsigned int u = ((const unsigned int*)(Wh + (size_t)p.x * 128))[lane];
            float wv = __int_as_float(p.y);
            a0 += b2f(u & 0xffffu) * wv;
            a1 += b2f(u >> 16) * wv;
        }
        const float inv = (end > beg) ? 1.0f / (float)(end - beg) : 0.0f;
        r0 += a0 * inv; r1 += a1 * inv;
    }

    const size_t o = out_off + (size_t)node * 128 + 2 * lane;
    if (*flag_p) {
        ushort2 s; s.x = f2b(r0); s.y = f2b(r1);
        *(ushort2*)((unsigned short*)out + o) = s;
    } else {
        *(float2*)((float*)out + o) = make_float2(r0, r1);
    }
}

// ---------------------------------------------------------------
extern "C" void kernel_launch(void* const* d_in, const int* in_sizes, int n_in,
                              void* d_out, int out_size, void* d_ws, size_t ws_size,
                              hipStream_t stream)
{
    const void* feat_word  = d_in[0];
    const void* feat_topic = d_in[1];
    const int* ww_src = (const int*)d_in[2];
    const int* ww_dst = (const int*)d_in[3];
    const void* ww_w = d_in[4];
    const int* wt_src = (const int*)d_in[5];
    const int* wt_dst = (const int*)d_in[6];
    const void* wt_w = d_in[7];
    const int* wd_src = (const int*)d_in[8];
    const int* wd_dst = (const int*)d_in[9];
    const void* wd_w = d_in[10];
    const int* td_src = (const int*)d_in[11];
    const int* td_dst = (const int*)d_in[12];
    const void* td_w = d_in[13];
    const int* tt_src = (const int*)d_in[14];
    const int* tt_dst = (const int*)d_in[15];
    const void* tt_w = d_in[16];
    const void* W_ww = d_in[17];
    const void* b_ww = d_in[18];
    const void* W_wt = d_in[19];
    const void* b_wt = d_in[20];
    const void* W_wd = d_in[21];
    const void* b_wd = d_in[22];
    const void* W_td = d_in[23];
    const void* b_td = d_in[24];
    const void* W_tt = d_in[25];
    const void* b_tt = d_in[26];

    const int E_ww = in_sizes[2];
    const int E_wt = in_sizes[5];
    const int E_wd = in_sizes[8];
    const int E_td = in_sizes[11];
    const int E_tt = in_sizes[14];

    // ---------------- workspace layout (bytes; total ~48.7 MB) ----------------
    char* ws = (char*)d_ws;
    unsigned int* flag = (unsigned int*)ws;                    // [0,4)
    int* cnt_base = (int*)(ws + 4);                            // 154,000 ints
    int* cnt_ww = cnt_base;
    int* cnt_wt = cnt_ww + 50000;
    int* cnt_tt = cnt_wt + 2000;
    int* cnt_wd = cnt_tt + 2000;
    int* cnt_td = cnt_wd + 50000;
    int* cur_base = cnt_base + 154000;                         // 154,000 ints
    int* cur_ww = cur_base;
    int* cur_wt = cur_ww + 50000;
    int* cur_tt = cur_wt + 2000;
    int* cur_wd = cur_tt + 2000;
    int* cur_td = cur_wd + 50000;
    int* rp_base = cur_base + 154000;                          // 154,005 ints
    int* rp_ww = rp_base;
    int* rp_wt = rp_ww + 50001;
    int* rp_tt = rp_wt + 2001;
    int* rp_wd = rp_tt + 2001;
    int* rp_td = rp_wd + 50001;
    size_t off = 4 + (size_t)(154000 + 154000 + 154005) * 4;   // 1,848,024
    off = (off + 15) & ~(size_t)15;                            // 1,848,032
    short8* Bsw_ww = (short8*)(ws + off); off += 65536;
    short8* Bsw_wt = (short8*)(ws + off); off += 65536;
    short8* Bsw_wd = (short8*)(ws + off); off += 65536;
    short8* Bsw_td = (short8*)(ws + off); off += 32768;
    short8* Bsw_tt = (short8*)(ws + off); off += 32768;
    unsigned short* bias_all = (unsigned short*)(ws + off); off += 5 * 128 * 2;
    off = (off + 15) & ~(size_t)15;
    unsigned short* Wh_ww = (unsigned short*)(ws + off); off += (size_t)N_WORD * 128 * 2;
    unsigned short* Wh_wt = (unsigned short*)(ws + off); off += (size_t)N_WORD * 128 * 2;
    unsigned short* Wh_tt = (unsigned short*)(ws + off); off += (size_t)N_TOPIC * 128 * 2;
    unsigned short* Wh_td = (unsigned short*)(ws + off); off += (size_t)N_TOPIC * 128 * 2;
    off = (off + 7) & ~(size_t)7;
    int2* pairs_ww = (int2*)(ws + off); off += (size_t)E_MAX * 8;
    int2* pairs_wt = (int2*)(ws + off); off += (size_t)E_MAX * 8;
    int2* pairs_tt = (int2*)(ws + off); off += (size_t)E_MAX * 8;
    int2* pairs_wd = (int2*)(ws + off); off += (size_t)E_MAX * 8;
    int2* pairs_td = (int2*)(ws + off); off += (size_t)E_MAX * 8;

    // Wh_wd staged in d_out (word-output region; doc gather runs first,
    // word gather overwrites this region last).
    unsigned short* Wh_wd = (unsigned short*)d_out;

    detect_kernel<<<1, 1, 0, stream>>>((const unsigned int*)feat_word, flag);
    hipMemsetAsync(cnt_base, 0, (size_t)(154000 + 154000) * 4, stream);

    swizzle_kernel<<<dim3(8, 5), 256, 0, stream>>>(
        W_ww, W_wt, W_wd, W_td, W_tt, b_ww, b_wt, b_wd, b_td, b_tt,
        Bsw_ww, Bsw_wt, Bsw_wd, Bsw_td, Bsw_tt, bias_all, flag);

    hist5_kernel<<<dim3((E_MAX + 255) / 256, 5), 256, 0, stream>>>(
        ww_dst, E_ww, cnt_ww, wt_dst, E_wt, cnt_wt, tt_dst, E_tt, cnt_tt,
        wd_dst, E_wd, cnt_wd, td_dst, E_td, cnt_td);

    scan5_kernel<<<5, 1024, 0, stream>>>(
        cnt_ww, rp_ww, N_WORD, cnt_wt, rp_wt, N_TOPIC, cnt_tt, rp_tt, N_TOPIC,
        cnt_wd, rp_wd, N_DOC, cnt_td, rp_td, N_DOC);

    build5_kernel<<<dim3((E_MAX + 255) / 256, 5), 256, 0, stream>>>(
        ww_src, ww_dst, ww_w, E_ww, rp_ww, cur_ww, pairs_ww,
        wt_src, wt_dst, wt_w, E_wt, rp_wt, cur_wt, pairs_wt,
        tt_src, tt_dst, tt_w, E_tt, rp_tt, cur_tt, pairs_tt,
        wd_src, wd_dst, wd_w, E_wd, rp_wd, cur_wd, pairs_wd,
        td_src, td_dst, td_w, E_td, rp_td, cur_td, pairs_td, flag);

    // projections: word (3 phases), topic (2 phases)
    gemm_mfma_kernel<8, 3><<<(N_WORD + 63) / 64, 256, 0, stream>>>(
        feat_word, N_WORD, Bsw_ww, Bsw_wt, Bsw_wd, bias_all, 0, 1, 2,
        Wh_ww, Wh_wt, Wh_wd, flag);
    gemm_mfma_kernel<4, 2><<<(N_TOPIC + 63) / 64, 256, 0, stream>>>(
        feat_topic, N_TOPIC, Bsw_tt, Bsw_td, (const short8*)nullptr, bias_all, 4, 3, 0,
        Wh_tt, Wh_td, (unsigned short*)nullptr, flag);

    // gathers: doc first (reads Wh_wd in d_out word region), word last.
    gather2_kernel<<<(N_DOC + 3) / 4, 256, 0, stream>>>(
        rp_wd, pairs_wd, Wh_wd, rp_td, pairs_td, Wh_td,
        d_out, N_DOC, (size_t)6656000, flag);
    gather2_kernel<<<(N_TOPIC + 3) / 4, 256, 0, stream>>>(
        rp_wt, pairs_wt, Wh_wt, rp_tt, pairs_tt, Wh_tt,
        d_out, N_TOPIC, (size_t)6400000, flag);
    gather1_kernel<<<(N_WORD + 3) / 4, 256, 0, stream>>>(
        rp_ww, pairs_ww, Wh_ww, d_out, N_WORD, 0, flag);
}

// Round 6
// 694.715 us; speedup vs baseline: 3.5291x; 1.1607x over previous
//
#include <hip/hip_runtime.h>

typedef short short8 __attribute__((ext_vector_type(8)));
typedef float floatx4 __attribute__((ext_vector_type(4)));

// ---------- bf16 helpers (raw ushort representation) ----------
__device__ __forceinline__ float b2f(unsigned int u16) {
    union { unsigned int i; float f; } v;
    v.i = u16 << 16;
    return v.f;
}
__device__ __forceinline__ unsigned short f2b(float f) {
    unsigned int i = __float_as_uint(f);
    unsigned int r = (i + 0x7FFFu + ((i >> 16) & 1u)) >> 16;  // RNE
    return (unsigned short)r;
}

#define N_WORD  50000
#define N_TOPIC 2000
#define N_DOC   50000
#define E_MAX   500000

// ---------------------------------------------------------------
// Input-dtype detection: flag=1 -> bf16 inputs, 0 -> f32 inputs.
// ---------------------------------------------------------------
__global__ void detect_kernel(const unsigned int* __restrict__ feat_u32,
                              unsigned int* __restrict__ flag)
{
    int cnt = 0;
    for (int i = 0; i < 256; ++i) {
        unsigned int u = feat_u32[i];
        int e = (u >> 7) & 0xFF;   // low ushort viewed as bf16: exponent
        if (e >= 110 && e <= 140) ++cnt;
    }
    *flag = (cnt > 128) ? 1u : 0u;
}

// ---------------------------------------------------------------
// Weight swizzle -> B-fragment order for mfma_f32_16x16x32_bf16:
// entry(s,t,lane) = 8 bf16 B[k=s*32+q*8+j][n=t*16+(lane&15)].
// Also canonicalizes the 5 biases to bf16. grid = (8, 5).
// ---------------------------------------------------------------
__global__ __launch_bounds__(256) void swizzle_kernel(
    const void* __restrict__ W0, const void* __restrict__ W1,
    const void* __restrict__ W2, const void* __restrict__ W3,
    const void* __restrict__ W4,
    const void* __restrict__ b0, const void* __restrict__ b1,
    const void* __restrict__ b2, const void* __restrict__ b3,
    const void* __restrict__ b4,
    short8* __restrict__ D0, short8* __restrict__ D1,
    short8* __restrict__ D2, short8* __restrict__ D3,
    short8* __restrict__ D4,
    unsigned short* __restrict__ bias_out,
    const unsigned int* __restrict__ flag_p)
{
    const int w = blockIdx.y;
    const void* W; const void* bs; short8* D; int S;
    switch (w) {
        case 0: W = W0; bs = b0; D = D0; S = 8; break;
        case 1: W = W1; bs = b1; D = D1; S = 8; break;
        case 2: W = W2; bs = b2; D = D2; S = 8; break;
        case 3: W = W3; bs = b3; D = D3; S = 4; break;
        default: W = W4; bs = b4; D = D4; S = 4; break;
    }
    const int n_entries = S * 8 * 64;
    const int mode = (int)*flag_p;
    for (int e = blockIdx.x * 256 + threadIdx.x; e < n_entries; e += 8 * 256) {
        const int lane = e & 63, t = (e >> 6) & 7, s = e >> 9;
        const int q = lane >> 4, n = t * 16 + (lane & 15);
        short8 val;
#pragma unroll
        for (int j = 0; j < 8; ++j) {
            const int k = s * 32 + q * 8 + j;
            unsigned short hv = mode ? ((const unsigned short*)W)[k * 128 + n]
                                     : f2b(((const float*)W)[k * 128 + n]);
            val[j] = (short)hv;
        }
        D[e] = val;
    }
    if (blockIdx.x == 0 && threadIdx.x < 128) {
        bias_out[w * 128 + threadIdx.x] =
            mode ? ((const unsigned short*)bs)[threadIdx.x]
                 : f2b(((const float*)bs)[threadIdx.x]);
    }
}

// ---------------------------------------------------------------
// MFMA GEMM body (device fn): NP projections of the same 16-row A strip.
// ---------------------------------------------------------------
template <int S, int NP>
__device__ __forceinline__ void gemm_body(
    const void* feat_, int n_rows, int bx,
    const short8* Ba, const short8* Bb, const short8* Bc,
    const unsigned short* bias_all, int ba, int bb, int bc,
    unsigned short* Oa, unsigned short* Ob, unsigned short* Oc,
    int mode_bf16)
{
    const int lane = threadIdx.x & 63;
    const int wave = threadIdx.x >> 6;
    const int row0 = (bx * 4 + wave) * 16;
    if (row0 >= n_rows) return;
    const int m = lane & 15, q = lane >> 4;
    const int K = S * 32;

    short8 a[S];
    if (mode_bf16) {
        const short8* arow = (const short8*)((const unsigned short*)feat_ + (size_t)(row0 + m) * K);
#pragma unroll
        for (int s = 0; s < S; ++s) a[s] = arow[s * 4 + q];
    } else {
        const float* arow = (const float*)feat_ + (size_t)(row0 + m) * K;
#pragma unroll
        for (int s = 0; s < S; ++s) {
            const float4 f0 = ((const float4*)arow)[s * 8 + q * 2];
            const float4 f1 = ((const float4*)arow)[s * 8 + q * 2 + 1];
            short8 t;
            t[0] = (short)f2b(f0.x); t[1] = (short)f2b(f0.y);
            t[2] = (short)f2b(f0.z); t[3] = (short)f2b(f0.w);
            t[4] = (short)f2b(f1.x); t[5] = (short)f2b(f1.y);
            t[6] = (short)f2b(f1.z); t[7] = (short)f2b(f1.w);
            a[s] = t;
        }
    }

#pragma unroll
    for (int p = 0; p < NP; ++p) {
        const short8* B = (p == 0) ? Ba : ((p == 1) ? Bb : Bc);
        const unsigned short* bias = bias_all + ((p == 0) ? ba : ((p == 1) ? bb : bc)) * 128;
        unsigned short* O = (p == 0) ? Oa : ((p == 1) ? Ob : Oc);

        floatx4 acc[8];
#pragma unroll
        for (int t = 0; t < 8; ++t) { acc[t][0] = 0.f; acc[t][1] = 0.f; acc[t][2] = 0.f; acc[t][3] = 0.f; }

#pragma unroll
        for (int s = 0; s < S; ++s) {
#pragma unroll
            for (int t = 0; t < 8; ++t) {
                short8 b = B[(s * 8 + t) * 64 + lane];
                acc[t] = __builtin_amdgcn_mfma_f32_16x16x32_bf16(a[s], b, acc[t], 0, 0, 0);
            }
        }

#pragma unroll
        for (int t = 0; t < 8; ++t) {
            const float bb_ = b2f((unsigned int)bias[t * 16 + m]);
#pragma unroll
            for (int r = 0; r < 4; ++r) {
                const int row = row0 + q * 4 + r;            // C/D: row=quad*4+reg
                O[(size_t)row * 128 + t * 16 + m] = f2b(acc[t][r] + bb_);
            }
        }
    }
}

// Fused GEMM: blocks [0,782) word (K=256, 3 proj), [782,814) topic (K=128, 2 proj).
__global__ __launch_bounds__(256) void gemm_all_kernel(
    const void* __restrict__ feat_word, const void* __restrict__ feat_topic,
    const short8* __restrict__ Bww, const short8* __restrict__ Bwt,
    const short8* __restrict__ Bwd, const short8* __restrict__ Btt,
    const short8* __restrict__ Btd,
    const unsigned short* __restrict__ bias_all,
    unsigned short* __restrict__ Wh_ww, unsigned short* __restrict__ Wh_wt,
    unsigned short* __restrict__ Wh_wd, unsigned short* __restrict__ Wh_tt,
    unsigned short* __restrict__ Wh_td,
    const unsigned int* __restrict__ flag_p)
{
    const int mode = (int)*flag_p;
    if (blockIdx.x < 782) {
        gemm_body<8, 3>(feat_word, N_WORD, blockIdx.x, Bww, Bwt, Bwd,
                        bias_all, 0, 1, 2, Wh_ww, Wh_wt, Wh_wd, mode);
    } else {
        gemm_body<4, 2>(feat_topic, N_TOPIC, blockIdx.x - 782, Btt, Btd,
                        (const short8*)nullptr, bias_all, 4, 3, 0,
                        Wh_tt, Wh_td, (unsigned short*)nullptr, mode);
    }
}

// ---------------------------------------------------------------
// CSR build, fused over 5 relations (grid.y = relation).
// Pairs are PACKED u32: (w_bf16 << 16) | src_u16  (all srcs < 65536).
// ---------------------------------------------------------------
__global__ void hist5_kernel(
    const int* d0, int n0, int* c0, const int* d1, int n1, int* c1,
    const int* d2, int n2, int* c2, const int* d3, int n3, int* c3,
    const int* d4, int n4, int* c4)
{
    const int* d; int n; int* c;
    switch (blockIdx.y) {
        case 0: d = d0; n = n0; c = c0; break;
        case 1: d = d1; n = n1; c = c1; break;
        case 2: d = d2; n = n2; c = c2; break;
        case 3: d = d3; n = n3; c = c3; break;
        default: d = d4; n = n4; c = c4; break;
    }
    int i = blockIdx.x * 256 + threadIdx.x;
    if (i < n) atomicAdd(&c[d[i]], 1);
}

__global__ __launch_bounds__(1024) void scan5_kernel(
    const int* c0, int* r0, int n0, const int* c1, int* r1, int n1,
    const int* c2, int* r2, int n2, const int* c3, int* r3, int n3,
    const int* c4, int* r4, int n4)
{
    const int* cnt; int* row_ptr; int n;
    switch (blockIdx.x) {
        case 0: cnt = c0; row_ptr = r0; n = n0; break;
        case 1: cnt = c1; row_ptr = r1; n = n1; break;
        case 2: cnt = c2; row_ptr = r2; n = n2; break;
        case 3: cnt = c3; row_ptr = r3; n = n3; break;
        default: cnt = c4; row_ptr = r4; n = n4; break;
    }
    __shared__ int sums[1024];
    const int t = threadIdx.x;
    const int chunk = (n + 1023) / 1024;
    int start = t * chunk; if (start > n) start = n;
    int end = start + chunk; if (end > n) end = n;

    int s = 0;
    for (int i = start; i < end; ++i) s += cnt[i];
    sums[t] = s;
    __syncthreads();
    for (int off = 1; off < 1024; off <<= 1) {
        int v = (t >= off) ? sums[t - off] : 0;
        __syncthreads();
        sums[t] += v;
        __syncthreads();
    }
    int run = (t == 0) ? 0 : sums[t - 1];
    for (int i = start; i < end; ++i) { row_ptr[i] = run; run += cnt[i]; }
    if (end == n) row_ptr[n] = run;
}

__global__ void build5_kernel(
    const int* s0, const int* d0, const void* w0, int n0, const int* r0, int* u0, unsigned int* p0,
    const int* s1, const int* d1, const void* w1, int n1, const int* r1, int* u1, unsigned int* p1,
    const int* s2, const int* d2, const void* w2, int n2, const int* r2, int* u2, unsigned int* p2,
    const int* s3, const int* d3, const void* w3, int n3, const int* r3, int* u3, unsigned int* p3,
    const int* s4, const int* d4, const void* w4, int n4, const int* r4, int* u4, unsigned int* p4,
    const unsigned int* __restrict__ flag_p)
{
    const int* src; const int* dst; const void* w_; int n;
    const int* rp; int* cur; unsigned int* pairs;
    switch (blockIdx.y) {
        case 0: src = s0; dst = d0; w_ = w0; n = n0; rp = r0; cur = u0; pairs = p0; break;
        case 1: src = s1; dst = d1; w_ = w1; n = n1; rp = r1; cur = u1; pairs = p1; break;
        case 2: src = s2; dst = d2; w_ = w2; n = n2; rp = r2; cur = u2; pairs = p2; break;
        case 3: src = s3; dst = d3; w_ = w3; n = n3; rp = r3; cur = u3; pairs = p3; break;
        default: src = s4; dst = d4; w_ = w4; n = n4; rp = r4; cur = u4; pairs = p4; break;
    }
    int i = blockIdx.x * 256 + threadIdx.x;
    if (i >= n) return;
    int d = dst[i];
    int pos = rp[d] + atomicAdd(&cur[d], 1);
    unsigned short wv16 = (*flag_p) ? ((const unsigned short*)w_)[i]
                                    : f2b(((const float*)w_)[i]);
    pairs[pos] = ((unsigned int)wv16 << 16) | (unsigned int)src[i];
}

// ---------------------------------------------------------------
// Gather: accumulate one relation's weighted mean for `node` (2 dims/lane).
// 4-way unrolled: 4 independent 256B row loads in flight.
// ---------------------------------------------------------------
__device__ __forceinline__ void accum_rel(
    const int* __restrict__ rp, const unsigned int* __restrict__ pairs,
    const unsigned short* __restrict__ Wh, int node, int lane,
    float& r0, float& r1)
{
    const int beg = rp[node], end = rp[node + 1];
    float a0 = 0.0f, a1 = 0.0f;
    int e = beg;
    for (; e + 3 < end; e += 4) {
        unsigned int p0 = pairs[e], p1 = pairs[e + 1];
        unsigned int p2 = pairs[e + 2], p3 = pairs[e + 3];
        unsigned int u0 = ((const unsigned int*)(Wh + (size_t)(p0 & 0xffffu) * 128))[lane];
        unsigned int u1 = ((const unsigned int*)(Wh + (size_t)(p1 & 0xffffu) * 128))[lane];
        unsigned int u2 = ((const unsigned int*)(Wh + (size_t)(p2 & 0xffffu) * 128))[lane];
        unsigned int u3 = ((const unsigned int*)(Wh + (size_t)(p3 & 0xffffu) * 128))[lane];
        float w0 = b2f(p0 >> 16), w1 = b2f(p1 >> 16);
        float w2 = b2f(p2 >> 16), w3 = b2f(p3 >> 16);
        a0 += b2f(u0 & 0xffffu) * w0 + b2f(u1 & 0xffffu) * w1
            + b2f(u2 & 0xffffu) * w2 + b2f(u3 & 0xffffu) * w3;
        a1 += b2f(u0 >> 16) * w0 + b2f(u1 >> 16) * w1
            + b2f(u2 >> 16) * w2 + b2f(u3 >> 16) * w3;
    }
    for (; e < end; ++e) {
        unsigned int p = pairs[e];
        unsigned int u = ((const unsigned int*)(Wh + (size_t)(p & 0xffffu) * 128))[lane];
        float wv = b2f(p >> 16);
        a0 += b2f(u & 0xffffu) * wv;
        a1 += b2f(u >> 16) * wv;
    }
    const float inv = (end > beg) ? 1.0f / (float)(end - beg) : 0.0f;
    r0 += a0 * inv; r1 += a1 * inv;
}

__device__ __forceinline__ void write_node(
    void* out, size_t out_off, int node, int lane, float r0, float r1, int mode)
{
    const size_t o = out_off + (size_t)node * 128 + 2 * lane;
    if (mode) {
        ushort2 s; s.x = f2b(r0); s.y = f2b(r1);
        *(ushort2*)((unsigned short*)out + o) = s;
    } else {
        *(float2*)((float*)out + o) = make_float2(r0, r1);
    }
}

// Fused gather: blocks [0,12500) word | [12500,13000) topic | [13000,25500) doc.
__global__ __launch_bounds__(256) void gather_all_kernel(
    const int* __restrict__ rp_ww, const unsigned int* __restrict__ pr_ww,
    const unsigned short* __restrict__ Wh_ww,
    const int* __restrict__ rp_wt, const unsigned int* __restrict__ pr_wt,
    const unsigned short* __restrict__ Wh_wt,
    const int* __restrict__ rp_tt, const unsigned int* __restrict__ pr_tt,
    const unsigned short* __restrict__ Wh_tt,
    const int* __restrict__ rp_wd, const unsigned int* __restrict__ pr_wd,
    const unsigned short* __restrict__ Wh_wd,
    const int* __restrict__ rp_td, const unsigned int* __restrict__ pr_td,
    const unsigned short* __restrict__ Wh_td,
    void* __restrict__ out,
    const unsigned int* __restrict__ flag_p)
{
    const int lane = threadIdx.x & 63;
    const int mode = (int)*flag_p;
    const int blk = blockIdx.x;
    float r0 = 0.0f, r1 = 0.0f;

    if (blk < 12500) {                       // h_word = mean_ww
        const int node = (blk * 256 + (int)threadIdx.x) >> 6;
        accum_rel(rp_ww, pr_ww, Wh_ww, node, lane, r0, r1);
        write_node(out, 0, node, lane, r0, r1, mode);
    } else if (blk < 13000) {                // h_topic = mean_wt + mean_tt
        const int node = ((blk - 12500) * 256 + (int)threadIdx.x) >> 6;
        accum_rel(rp_wt, pr_wt, Wh_wt, node, lane, r0, r1);
        accum_rel(rp_tt, pr_tt, Wh_tt, node, lane, r0, r1);
        write_node(out, (size_t)6400000, node, lane, r0, r1, mode);
    } else {                                 // h_doc = mean_wd + mean_td
        const int node = ((blk - 13000) * 256 + (int)threadIdx.x) >> 6;
        accum_rel(rp_wd, pr_wd, Wh_wd, node, lane, r0, r1);
        accum_rel(rp_td, pr_td, Wh_td, node, lane, r0, r1);
        write_node(out, (size_t)6656000, node, lane, r0, r1, mode);
    }
}

// ---------------------------------------------------------------
extern "C" void kernel_launch(void* const* d_in, const int* in_sizes, int n_in,
                              void* d_out, int out_size, void* d_ws, size_t ws_size,
                              hipStream_t stream)
{
    const void* feat_word  = d_in[0];
    const void* feat_topic = d_in[1];
    const int* ww_src = (const int*)d_in[2];
    const int* ww_dst = (const int*)d_in[3];
    const void* ww_w = d_in[4];
    const int* wt_src = (const int*)d_in[5];
    const int* wt_dst = (const int*)d_in[6];
    const void* wt_w = d_in[7];
    const int* wd_src = (const int*)d_in[8];
    const int* wd_dst = (const int*)d_in[9];
    const void* wd_w = d_in[10];
    const int* td_src = (const int*)d_in[11];
    const int* td_dst = (const int*)d_in[12];
    const void* td_w = d_in[13];
    const int* tt_src = (const int*)d_in[14];
    const int* tt_dst = (const int*)d_in[15];
    const void* tt_w = d_in[16];
    const void* W_ww = d_in[17];
    const void* b_ww = d_in[18];
    const void* W_wt = d_in[19];
    const void* b_wt = d_in[20];
    const void* W_wd = d_in[21];
    const void* b_wd = d_in[22];
    const void* W_td = d_in[23];
    const void* b_td = d_in[24];
    const void* W_tt = d_in[25];
    const void* b_tt = d_in[26];

    const int E_ww = in_sizes[2];
    const int E_wt = in_sizes[5];
    const int E_wd = in_sizes[8];
    const int E_td = in_sizes[11];
    const int E_tt = in_sizes[14];

    // ---------------- workspace layout (~51.5 MB; <=52.8 MB proven OK) ----
    char* ws = (char*)d_ws;
    unsigned int* flag = (unsigned int*)ws;                    // [0,4)
    int* cnt_base = (int*)(ws + 4);                            // 154,000 ints
    int* cnt_ww = cnt_base;
    int* cnt_wt = cnt_ww + 50000;
    int* cnt_tt = cnt_wt + 2000;
    int* cnt_wd = cnt_tt + 2000;
    int* cnt_td = cnt_wd + 50000;
    int* cur_base = cnt_base + 154000;                         // 154,000 ints
    int* cur_ww = cur_base;
    int* cur_wt = cur_ww + 50000;
    int* cur_tt = cur_wt + 2000;
    int* cur_wd = cur_tt + 2000;
    int* cur_td = cur_wd + 50000;
    int* rp_base = cur_base + 154000;                          // 154,005 ints
    int* rp_ww = rp_base;
    int* rp_wt = rp_ww + 50001;
    int* rp_tt = rp_wt + 2001;
    int* rp_wd = rp_tt + 2001;
    int* rp_td = rp_wd + 50001;
    size_t off = 4 + (size_t)(154000 + 154000 + 154005) * 4;   // 1,848,024
    off = (off + 15) & ~(size_t)15;                            // 1,848,032
    short8* Bsw_ww = (short8*)(ws + off); off += 65536;
    short8* Bsw_wt = (short8*)(ws + off); off += 65536;
    short8* Bsw_wd = (short8*)(ws + off); off += 65536;
    short8* Bsw_td = (short8*)(ws + off); off += 32768;
    short8* Bsw_tt = (short8*)(ws + off); off += 32768;
    unsigned short* bias_all = (unsigned short*)(ws + off); off += 5 * 128 * 2;
    off = (off + 15) & ~(size_t)15;
    unsigned short* Wh_ww = (unsigned short*)(ws + off); off += (size_t)N_WORD * 128 * 2;
    unsigned short* Wh_wt = (unsigned short*)(ws + off); off += (size_t)N_WORD * 128 * 2;
    unsigned short* Wh_wd = (unsigned short*)(ws + off); off += (size_t)N_WORD * 128 * 2;
    unsigned short* Wh_tt = (unsigned short*)(ws + off); off += (size_t)N_TOPIC * 128 * 2;
    unsigned short* Wh_td = (unsigned short*)(ws + off); off += (size_t)N_TOPIC * 128 * 2;
    off = (off + 3) & ~(size_t)3;
    unsigned int* pairs_ww = (unsigned int*)(ws + off); off += (size_t)E_MAX * 4;
    unsigned int* pairs_wt = (unsigned int*)(ws + off); off += (size_t)E_MAX * 4;
    unsigned int* pairs_tt = (unsigned int*)(ws + off); off += (size_t)E_MAX * 4;
    unsigned int* pairs_wd = (unsigned int*)(ws + off); off += (size_t)E_MAX * 4;
    unsigned int* pairs_td = (unsigned int*)(ws + off); off += (size_t)E_MAX * 4;

    detect_kernel<<<1, 1, 0, stream>>>((const unsigned int*)feat_word, flag);
    hipMemsetAsync(cnt_base, 0, (size_t)(154000 + 154000) * 4, stream);

    swizzle_kernel<<<dim3(8, 5), 256, 0, stream>>>(
        W_ww, W_wt, W_wd, W_td, W_tt, b_ww, b_wt, b_wd, b_td, b_tt,
        Bsw_ww, Bsw_wt, Bsw_wd, Bsw_td, Bsw_tt, bias_all, flag);

    hist5_kernel<<<dim3((E_MAX + 255) / 256, 5), 256, 0, stream>>>(
        ww_dst, E_ww, cnt_ww, wt_dst, E_wt, cnt_wt, tt_dst, E_tt, cnt_tt,
        wd_dst, E_wd, cnt_wd, td_dst, E_td, cnt_td);

    scan5_kernel<<<5, 1024, 0, stream>>>(
        cnt_ww, rp_ww, N_WORD, cnt_wt, rp_wt, N_TOPIC, cnt_tt, rp_tt, N_TOPIC,
        cnt_wd, rp_wd, N_DOC, cnt_td, rp_td, N_DOC);

    build5_kernel<<<dim3((E_MAX + 255) / 256, 5), 256, 0, stream>>>(
        ww_src, ww_dst, ww_w, E_ww, rp_ww, cur_ww, pairs_ww,
        wt_src, wt_dst, wt_w, E_wt, rp_wt, cur_wt, pairs_wt,
        tt_src, tt_dst, tt_w, E_tt, rp_tt, cur_tt, pairs_tt,
        wd_src, wd_dst, wd_w, E_wd, rp_wd, cur_wd, pairs_wd,
        td_src, td_dst, td_w, E_td, rp_td, cur_td, pairs_td, flag);

    // fused projections: word strip blocks + topic strip blocks
    gemm_all_kernel<<<782 + 32, 256, 0, stream>>>(
        feat_word, feat_topic, Bsw_ww, Bsw_wt, Bsw_wd, Bsw_tt, Bsw_td,
        bias_all, Wh_ww, Wh_wt, Wh_wd, Wh_tt, Wh_td, flag);

    // fused gathers: word | topic | doc
    gather_all_kernel<<<12500 + 500 + 12500, 256, 0, stream>>>(
        rp_ww, pairs_ww, Wh_ww, rp_wt, pairs_wt, Wh_wt, rp_tt, pairs_tt, Wh_tt,
        rp_wd, pairs_wd, Wh_wd, rp_td, pairs_td, Wh_td, d_out, flag);
}

// Round 7
// 694.635 us; speedup vs baseline: 3.5295x; 1.0001x over previous
//
#include <hip/hip_runtime.h>

typedef short short8 __attribute__((ext_vector_type(8)));
typedef float floatx4 __attribute__((ext_vector_type(4)));

// ---------- bf16 helpers (raw ushort representation) ----------
__device__ __forceinline__ float b2f(unsigned int u16) {
    union { unsigned int i; float f; } v;
    v.i = u16 << 16;
    return v.f;
}
__device__ __forceinline__ unsigned short f2b(float f) {
    unsigned int i = __float_as_uint(f);
    unsigned int r = (i + 0x7FFFu + ((i >> 16) & 1u)) >> 16;  // RNE
    return (unsigned short)r;
}

#define N_WORD  50000
#define N_TOPIC 2000
#define N_DOC   50000
#define E_MAX   500000

// ---------------------------------------------------------------
// Input-dtype detection: flag=1 -> bf16 inputs, 0 -> f32 inputs.
// ---------------------------------------------------------------
__global__ void detect_kernel(const unsigned int* __restrict__ feat_u32,
                              unsigned int* __restrict__ flag)
{
    int cnt = 0;
    for (int i = 0; i < 256; ++i) {
        unsigned int u = feat_u32[i];
        int e = (u >> 7) & 0xFF;
        if (e >= 110 && e <= 140) ++cnt;
    }
    *flag = (cnt > 128) ? 1u : 0u;
}

// ---------------------------------------------------------------
// Weight swizzle -> B-fragment order for mfma_f32_16x16x32_bf16.
// ---------------------------------------------------------------
__global__ __launch_bounds__(256) void swizzle_kernel(
    const void* __restrict__ W0, const void* __restrict__ W1,
    const void* __restrict__ W2, const void* __restrict__ W3,
    const void* __restrict__ W4,
    const void* __restrict__ b0, const void* __restrict__ b1,
    const void* __restrict__ b2, const void* __restrict__ b3,
    const void* __restrict__ b4,
    short8* __restrict__ D0, short8* __restrict__ D1,
    short8* __restrict__ D2, short8* __restrict__ D3,
    short8* __restrict__ D4,
    unsigned short* __restrict__ bias_out,
    const unsigned int* __restrict__ flag_p)
{
    const int w = blockIdx.y;
    const void* W; const void* bs; short8* D; int S;
    switch (w) {
        case 0: W = W0; bs = b0; D = D0; S = 8; break;
        case 1: W = W1; bs = b1; D = D1; S = 8; break;
        case 2: W = W2; bs = b2; D = D2; S = 8; break;
        case 3: W = W3; bs = b3; D = D3; S = 4; break;
        default: W = W4; bs = b4; D = D4; S = 4; break;
    }
    const int n_entries = S * 8 * 64;
    const int mode = (int)*flag_p;
    for (int e = blockIdx.x * 256 + threadIdx.x; e < n_entries; e += 8 * 256) {
        const int lane = e & 63, t = (e >> 6) & 7, s = e >> 9;
        const int q = lane >> 4, n = t * 16 + (lane & 15);
        short8 val;
#pragma unroll
        for (int j = 0; j < 8; ++j) {
            const int k = s * 32 + q * 8 + j;
            unsigned short hv = mode ? ((const unsigned short*)W)[k * 128 + n]
                                     : f2b(((const float*)W)[k * 128 + n]);
            val[j] = (short)hv;
        }
        D[e] = val;
    }
    if (blockIdx.x == 0 && threadIdx.x < 128) {
        bias_out[w * 128 + threadIdx.x] =
            mode ? ((const unsigned short*)bs)[threadIdx.x]
                 : f2b(((const float*)bs)[threadIdx.x]);
    }
}

// ---------------------------------------------------------------
// MFMA GEMM body: NP projections of one 16-row A strip.
// ---------------------------------------------------------------
template <int S, int NP>
__device__ __forceinline__ void gemm_body(
    const void* feat_, int n_rows, int bx,
    const short8* Ba, const short8* Bb, const short8* Bc,
    const unsigned short* bias_all, int ba, int bb, int bc,
    unsigned short* Oa, unsigned short* Ob, unsigned short* Oc,
    int mode_bf16)
{
    const int lane = threadIdx.x & 63;
    const int wave = threadIdx.x >> 6;
    const int row0 = (bx * 4 + wave) * 16;
    if (row0 >= n_rows) return;
    const int m = lane & 15, q = lane >> 4;
    const int K = S * 32;

    short8 a[S];
    if (mode_bf16) {
        const short8* arow = (const short8*)((const unsigned short*)feat_ + (size_t)(row0 + m) * K);
#pragma unroll
        for (int s = 0; s < S; ++s) a[s] = arow[s * 4 + q];
    } else {
        const float* arow = (const float*)feat_ + (size_t)(row0 + m) * K;
#pragma unroll
        for (int s = 0; s < S; ++s) {
            const float4 f0 = ((const float4*)arow)[s * 8 + q * 2];
            const float4 f1 = ((const float4*)arow)[s * 8 + q * 2 + 1];
            short8 t;
            t[0] = (short)f2b(f0.x); t[1] = (short)f2b(f0.y);
            t[2] = (short)f2b(f0.z); t[3] = (short)f2b(f0.w);
            t[4] = (short)f2b(f1.x); t[5] = (short)f2b(f1.y);
            t[6] = (short)f2b(f1.z); t[7] = (short)f2b(f1.w);
            a[s] = t;
        }
    }

#pragma unroll
    for (int p = 0; p < NP; ++p) {
        const short8* B = (p == 0) ? Ba : ((p == 1) ? Bb : Bc);
        const unsigned short* bias = bias_all + ((p == 0) ? ba : ((p == 1) ? bb : bc)) * 128;
        unsigned short* O = (p == 0) ? Oa : ((p == 1) ? Ob : Oc);

        floatx4 acc[8];
#pragma unroll
        for (int t = 0; t < 8; ++t) { acc[t][0] = 0.f; acc[t][1] = 0.f; acc[t][2] = 0.f; acc[t][3] = 0.f; }

#pragma unroll
        for (int s = 0; s < S; ++s) {
#pragma unroll
            for (int t = 0; t < 8; ++t) {
                short8 b = B[(s * 8 + t) * 64 + lane];
                acc[t] = __builtin_amdgcn_mfma_f32_16x16x32_bf16(a[s], b, acc[t], 0, 0, 0);
            }
        }

#pragma unroll
        for (int t = 0; t < 8; ++t) {
            const float bb_ = b2f((unsigned int)bias[t * 16 + m]);
#pragma unroll
            for (int r = 0; r < 4; ++r) {
                const int row = row0 + q * 4 + r;
                O[(size_t)row * 128 + t * 16 + m] = f2b(acc[t][r] + bb_);
            }
        }
    }
}

__global__ __launch_bounds__(256) void gemm_all_kernel(
    const void* __restrict__ feat_word, const void* __restrict__ feat_topic,
    const short8* __restrict__ Bww, const short8* __restrict__ Bwt,
    const short8* __restrict__ Bwd, const short8* __restrict__ Btt,
    const short8* __restrict__ Btd,
    const unsigned short* __restrict__ bias_all,
    unsigned short* __restrict__ Wh_ww, unsigned short* __restrict__ Wh_wt,
    unsigned short* __restrict__ Wh_wd, unsigned short* __restrict__ Wh_tt,
    unsigned short* __restrict__ Wh_td,
    const unsigned int* __restrict__ flag_p)
{
    const int mode = (int)*flag_p;
    if (blockIdx.x < 782) {
        gemm_body<8, 3>(feat_word, N_WORD, blockIdx.x, Bww, Bwt, Bwd,
                        bias_all, 0, 1, 2, Wh_ww, Wh_wt, Wh_wd, mode);
    } else {
        gemm_body<4, 2>(feat_topic, N_TOPIC, blockIdx.x - 782, Btt, Btd,
                        (const short8*)nullptr, bias_all, 4, 3, 0,
                        Wh_tt, Wh_td, (unsigned short*)nullptr, mode);
    }
}

// ---------------------------------------------------------------
// XCD-cohort CSR build. Cohort c = blockIdx.x & 7 owns dst range
// [c*range, (c+1)*range): all cnt/cursor/pairs lines of that range are
// written by (heuristically) one XCD only -> L2 merges partial lines.
// ---------------------------------------------------------------
__global__ void hist5_kernel(
    const int* d0, int n0, int* c0, const int* d1, int n1, int* c1,
    const int* d2, int n2, int* c2, const int* d3, int n3, int* c3,
    const int* d4, int n4, int* c4)
{
    const int* d; int n; int* c; int range;
    switch (blockIdx.y) {
        case 0: d = d0; n = n0; c = c0; range = 6250; break;
        case 1: d = d1; n = n1; c = c1; range = 250;  break;
        case 2: d = d2; n = n2; c = c2; range = 250;  break;
        case 3: d = d3; n = n3; c = c3; range = 6250; break;
        default: d = d4; n = n4; c = c4; range = 6250; break;
    }
    const int cohort = blockIdx.x & 7;
    const int bi = blockIdx.x >> 3;
    const int nb = gridDim.x >> 3;
    const int lo = cohort * range, hi = lo + range;
    for (int i = bi * 256 + threadIdx.x; i < n; i += nb * 256) {
        int dd = d[i];
        if (dd >= lo && dd < hi) atomicAdd(&c[dd], 1);
    }
}

__global__ __launch_bounds__(1024) void scan5_kernel(
    const int* c0, int* r0, int n0, const int* c1, int* r1, int n1,
    const int* c2, int* r2, int n2, const int* c3, int* r3, int n3,
    const int* c4, int* r4, int n4)
{
    const int* cnt; int* row_ptr; int n;
    switch (blockIdx.x) {
        case 0: cnt = c0; row_ptr = r0; n = n0; break;
        case 1: cnt = c1; row_ptr = r1; n = n1; break;
        case 2: cnt = c2; row_ptr = r2; n = n2; break;
        case 3: cnt = c3; row_ptr = r3; n = n3; break;
        default: cnt = c4; row_ptr = r4; n = n4; break;
    }
    __shared__ int sums[1024];
    const int t = threadIdx.x;
    const int chunk = (n + 1023) / 1024;
    int start = t * chunk; if (start > n) start = n;
    int end = start + chunk; if (end > n) end = n;

    int s = 0;
    for (int i = start; i < end; ++i) s += cnt[i];
    sums[t] = s;
    __syncthreads();
    for (int off = 1; off < 1024; off <<= 1) {
        int v = (t >= off) ? sums[t - off] : 0;
        __syncthreads();
        sums[t] += v;
        __syncthreads();
    }
    int run = (t == 0) ? 0 : sums[t - 1];
    for (int i = start; i < end; ++i) { row_ptr[i] = run; run += cnt[i]; }
    if (end == n) row_ptr[n] = run;
}

__global__ void build5_kernel(
    const int* s0, const int* d0, const void* w0, int n0, const int* r0, int* u0, unsigned int* p0,
    const int* s1, const int* d1, const void* w1, int n1, const int* r1, int* u1, unsigned int* p1,
    const int* s2, const int* d2, const void* w2, int n2, const int* r2, int* u2, unsigned int* p2,
    const int* s3, const int* d3, const void* w3, int n3, const int* r3, int* u3, unsigned int* p3,
    const int* s4, const int* d4, const void* w4, int n4, const int* r4, int* u4, unsigned int* p4,
    const unsigned int* __restrict__ flag_p)
{
    const int* src; const int* dst; const void* w_; int n;
    const int* rp; int* cur; unsigned int* pairs; int range;
    switch (blockIdx.y) {
        case 0: src = s0; dst = d0; w_ = w0; n = n0; rp = r0; cur = u0; pairs = p0; range = 6250; break;
        case 1: src = s1; dst = d1; w_ = w1; n = n1; rp = r1; cur = u1; pairs = p1; range = 250;  break;
        case 2: src = s2; dst = d2; w_ = w2; n = n2; rp = r2; cur = u2; pairs = p2; range = 250;  break;
        case 3: src = s3; dst = d3; w_ = w3; n = n3; rp = r3; cur = u3; pairs = p3; range = 6250; break;
        default: src = s4; dst = d4; w_ = w4; n = n4; rp = r4; cur = u4; pairs = p4; range = 6250; break;
    }
    const int cohort = blockIdx.x & 7;
    const int bi = blockIdx.x >> 3;
    const int nb = gridDim.x >> 3;
    const int lo = cohort * range, hi = lo + range;
    const int mode = (int)*flag_p;
    for (int i = bi * 256 + threadIdx.x; i < n; i += nb * 256) {
        int d = dst[i];
        if (d < lo || d >= hi) continue;
        int pos = rp[d] + atomicAdd(&cur[d], 1);
        unsigned short wv16 = mode ? ((const unsigned short*)w_)[i]
                                   : f2b(((const float*)w_)[i]);
        pairs[pos] = ((unsigned int)wv16 << 16) | (unsigned int)src[i];
    }
}

// ---------------------------------------------------------------
// Gather: 32 lanes per edge (2 nodes/wave), 4 dims per lane (uint2 row
// loads), 4-way edge unroll -> 8 independent 256B row reads per wave.
// ---------------------------------------------------------------
__device__ __forceinline__ void accum_rel32(
    const int* __restrict__ rp, const unsigned int* __restrict__ pairs,
    const unsigned short* __restrict__ Wh, int node, int sl,
    float4& r)
{
    const int beg = rp[node], end = rp[node + 1];
    float ax = 0.f, ay = 0.f, az = 0.f, aw = 0.f;
    int e = beg;
    for (; e + 3 < end; e += 4) {
        unsigned int p0 = pairs[e], p1 = pairs[e + 1];
        unsigned int p2 = pairs[e + 2], p3 = pairs[e + 3];
        uint2 u0 = ((const uint2*)(Wh + (size_t)(p0 & 0xffffu) * 128))[sl];
        uint2 u1 = ((const uint2*)(Wh + (size_t)(p1 & 0xffffu) * 128))[sl];
        uint2 u2 = ((const uint2*)(Wh + (size_t)(p2 & 0xffffu) * 128))[sl];
        uint2 u3 = ((const uint2*)(Wh + (size_t)(p3 & 0xffffu) * 128))[sl];
        float w0 = b2f(p0 >> 16), w1 = b2f(p1 >> 16);
        float w2 = b2f(p2 >> 16), w3 = b2f(p3 >> 16);
        ax += b2f(u0.x & 0xffffu) * w0 + b2f(u1.x & 0xffffu) * w1
            + b2f(u2.x & 0xffffu) * w2 + b2f(u3.x & 0xffffu) * w3;
        ay += b2f(u0.x >> 16) * w0 + b2f(u1.x >> 16) * w1
            + b2f(u2.x >> 16) * w2 + b2f(u3.x >> 16) * w3;
        az += b2f(u0.y & 0xffffu) * w0 + b2f(u1.y & 0xffffu) * w1
            + b2f(u2.y & 0xffffu) * w2 + b2f(u3.y & 0xffffu) * w3;
        aw += b2f(u0.y >> 16) * w0 + b2f(u1.y >> 16) * w1
            + b2f(u2.y >> 16) * w2 + b2f(u3.y >> 16) * w3;
    }
    for (; e < end; ++e) {
        unsigned int p = pairs[e];
        uint2 u = ((const uint2*)(Wh + (size_t)(p & 0xffffu) * 128))[sl];
        float wv = b2f(p >> 16);
        ax += b2f(u.x & 0xffffu) * wv; ay += b2f(u.x >> 16) * wv;
        az += b2f(u.y & 0xffffu) * wv; aw += b2f(u.y >> 16) * wv;
    }
    const float inv = (end > beg) ? 1.0f / (float)(end - beg) : 0.0f;
    r.x += ax * inv; r.y += ay * inv; r.z += az * inv; r.w += aw * inv;
}

__device__ __forceinline__ void write_node32(
    void* out, size_t out_off, int node, int sl, float4 r, int mode)
{
    const size_t o = out_off + (size_t)node * 128 + sl * 4;
    if (mode) {
        ushort4 s;
        s.x = f2b(r.x); s.y = f2b(r.y); s.z = f2b(r.z); s.w = f2b(r.w);
        *(ushort4*)((unsigned short*)out + o) = s;
    } else {
        *(float4*)((float*)out + o) = r;
    }
}

// blocks: [0,6250) word | [6250,6500) topic | [6500,12750) doc; 8 nodes/block.
__global__ __launch_bounds__(256) void gather_all_kernel(
    const int* __restrict__ rp_ww, const unsigned int* __restrict__ pr_ww,
    const unsigned short* __restrict__ Wh_ww,
    const int* __restrict__ rp_wt, const unsigned int* __restrict__ pr_wt,
    const unsigned short* __restrict__ Wh_wt,
    const int* __restrict__ rp_tt, const unsigned int* __restrict__ pr_tt,
    const unsigned short* __restrict__ Wh_tt,
    const int* __restrict__ rp_wd, const unsigned int* __restrict__ pr_wd,
    const unsigned short* __restrict__ Wh_wd,
    const int* __restrict__ rp_td, const unsigned int* __restrict__ pr_td,
    const unsigned short* __restrict__ Wh_td,
    void* __restrict__ out,
    const unsigned int* __restrict__ flag_p)
{
    const int half = threadIdx.x >> 5;     // 0..7
    const int sl = threadIdx.x & 31;
    const int mode = (int)*flag_p;
    const int blk = blockIdx.x;
    float4 r = make_float4(0.f, 0.f, 0.f, 0.f);

    if (blk < 6250) {                        // h_word = mean_ww
        const int node = blk * 8 + half;
        accum_rel32(rp_ww, pr_ww, Wh_ww, node, sl, r);
        write_node32(out, 0, node, sl, r, mode);
    } else if (blk < 6500) {                 // h_topic = mean_wt + mean_tt
        const int node = (blk - 6250) * 8 + half;
        accum_rel32(rp_wt, pr_wt, Wh_wt, node, sl, r);
        accum_rel32(rp_tt, pr_tt, Wh_tt, node, sl, r);
        write_node32(out, (size_t)6400000, node, sl, r, mode);
    } else {                                 // h_doc = mean_wd + mean_td
        const int node = (blk - 6500) * 8 + half;
        accum_rel32(rp_wd, pr_wd, Wh_wd, node, sl, r);
        accum_rel32(rp_td, pr_td, Wh_td, node, sl, r);
        write_node32(out, (size_t)6656000, node, sl, r, mode);
    }
}

// ---------------------------------------------------------------
extern "C" void kernel_launch(void* const* d_in, const int* in_sizes, int n_in,
                              void* d_out, int out_size, void* d_ws, size_t ws_size,
                              hipStream_t stream)
{
    const void* feat_word  = d_in[0];
    const void* feat_topic = d_in[1];
    const int* ww_src = (const int*)d_in[2];
    const int* ww_dst = (const int*)d_in[3];
    const void* ww_w = d_in[4];
    const int* wt_src = (const int*)d_in[5];
    const int* wt_dst = (const int*)d_in[6];
    const void* wt_w = d_in[7];
    const int* wd_src = (const int*)d_in[8];
    const int* wd_dst = (const int*)d_in[9];
    const void* wd_w = d_in[10];
    const int* td_src = (const int*)d_in[11];
    const int* td_dst = (const int*)d_in[12];
    const void* td_w = d_in[13];
    const int* tt_src = (const int*)d_in[14];
    const int* tt_dst = (const int*)d_in[15];
    const void* tt_w = d_in[16];
    const void* W_ww = d_in[17];
    const void* b_ww = d_in[18];
    const void* W_wt = d_in[19];
    const void* b_wt = d_in[20];
    const void* W_wd = d_in[21];
    const void* b_wd = d_in[22];
    const void* W_td = d_in[23];
    const void* b_td = d_in[24];
    const void* W_tt = d_in[25];
    const void* b_tt = d_in[26];

    const int E_ww = in_sizes[2];
    const int E_wt = in_sizes[5];
    const int E_wd = in_sizes[8];
    const int E_td = in_sizes[11];
    const int E_tt = in_sizes[14];

    // ---------------- workspace layout (~51.5 MB) ----------------
    char* ws = (char*)d_ws;
    unsigned int* flag = (unsigned int*)ws;
    int* cnt_base = (int*)(ws + 4);
    int* cnt_ww = cnt_base;
    int* cnt_wt = cnt_ww + 50000;
    int* cnt_tt = cnt_wt + 2000;
    int* cnt_wd = cnt_tt + 2000;
    int* cnt_td = cnt_wd + 50000;
    int* cur_base = cnt_base + 154000;
    int* cur_ww = cur_base;
    int* cur_wt = cur_ww + 50000;
    int* cur_tt = cur_wt + 2000;
    int* cur_wd = cur_tt + 2000;
    int* cur_td = cur_wd + 50000;
    int* rp_base = cur_base + 154000;
    int* rp_ww = rp_base;
    int* rp_wt = rp_ww + 50001;
    int* rp_tt = rp_wt + 2001;
    int* rp_wd = rp_tt + 2001;
    int* rp_td = rp_wd + 50001;
    size_t off = 4 + (size_t)(154000 + 154000 + 154005) * 4;
    off = (off + 15) & ~(size_t)15;
    short8* Bsw_ww = (short8*)(ws + off); off += 65536;
    short8* Bsw_wt = (short8*)(ws + off); off += 65536;
    short8* Bsw_wd = (short8*)(ws + off); off += 65536;
    short8* Bsw_td = (short8*)(ws + off); off += 32768;
    short8* Bsw_tt = (short8*)(ws + off); off += 32768;
    unsigned short* bias_all = (unsigned short*)(ws + off); off += 5 * 128 * 2;
    off = (off + 15) & ~(size_t)15;
    unsigned short* Wh_ww = (unsigned short*)(ws + off); off += (size_t)N_WORD * 128 * 2;
    unsigned short* Wh_wt = (unsigned short*)(ws + off); off += (size_t)N_WORD * 128 * 2;
    unsigned short* Wh_wd = (unsigned short*)(ws + off); off += (size_t)N_WORD * 128 * 2;
    unsigned short* Wh_tt = (unsigned short*)(ws + off); off += (size_t)N_TOPIC * 128 * 2;
    unsigned short* Wh_td = (unsigned short*)(ws + off); off += (size_t)N_TOPIC * 128 * 2;
    off = (off + 3) & ~(size_t)3;
    unsigned int* pairs_ww = (unsigned int*)(ws + off); off += (size_t)E_MAX * 4;
    unsigned int* pairs_wt = (unsigned int*)(ws + off); off += (size_t)E_MAX * 4;
    unsigned int* pairs_tt = (unsigned int*)(ws + off); off += (size_t)E_MAX * 4;
    unsigned int* pairs_wd = (unsigned int*)(ws + off); off += (size_t)E_MAX * 4;
    unsigned int* pairs_td = (unsigned int*)(ws + off); off += (size_t)E_MAX * 4;

    detect_kernel<<<1, 1, 0, stream>>>((const unsigned int*)feat_word, flag);
    hipMemsetAsync(cnt_base, 0, (size_t)(154000 + 154000) * 4, stream);

    swizzle_kernel<<<dim3(8, 5), 256, 0, stream>>>(
        W_ww, W_wt, W_wd, W_td, W_tt, b_ww, b_wt, b_wd, b_td, b_tt,
        Bsw_ww, Bsw_wt, Bsw_wd, Bsw_td, Bsw_tt, bias_all, flag);

    // cohort-partitioned hist/build: gridDim.x multiple of 8
    hist5_kernel<<<dim3(512, 5), 256, 0, stream>>>(
        ww_dst, E_ww, cnt_ww, wt_dst, E_wt, cnt_wt, tt_dst, E_tt, cnt_tt,
        wd_dst, E_wd, cnt_wd, td_dst, E_td, cnt_td);

    scan5_kernel<<<5, 1024, 0, stream>>>(
        cnt_ww, rp_ww, N_WORD, cnt_wt, rp_wt, N_TOPIC, cnt_tt, rp_tt, N_TOPIC,
        cnt_wd, rp_wd, N_DOC, cnt_td, rp_td, N_DOC);

    build5_kernel<<<dim3(512, 5), 256, 0, stream>>>(
        ww_src, ww_dst, ww_w, E_ww, rp_ww, cur_ww, pairs_ww,
        wt_src, wt_dst, wt_w, E_wt, rp_wt, cur_wt, pairs_wt,
        tt_src, tt_dst, tt_w, E_tt, rp_tt, cur_tt, pairs_tt,
        wd_src, wd_dst, wd_w, E_wd, rp_wd, cur_wd, pairs_wd,
        td_src, td_dst, td_w, E_td, rp_td, cur_td, pairs_td, flag);

    gemm_all_kernel<<<782 + 32, 256, 0, stream>>>(
        feat_word, feat_topic, Bsw_ww, Bsw_wt, Bsw_wd, Bsw_tt, Bsw_td,
        bias_all, Wh_ww, Wh_wt, Wh_wd, Wh_tt, Wh_td, flag);

    gather_all_kernel<<<6250 + 250 + 6250, 256, 0, stream>>>(
        rp_ww, pairs_ww, Wh_ww, rp_wt, pairs_wt, Wh_wt, rp_tt, pairs_tt, Wh_tt,
        rp_wd, pairs_wd, Wh_wd, rp_td, pairs_td, Wh_td, d_out, flag);
}

// Round 8
// 486.170 us; speedup vs baseline: 5.0429x; 1.4288x over previous
//
#include <hip/hip_runtime.h>

typedef short short8 __attribute__((ext_vector_type(8)));
typedef float floatx4 __attribute__((ext_vector_type(4)));

// ---------- bf16 helpers (raw ushort representation) ----------
__device__ __forceinline__ float b2f(unsigned int u16) {
    union { unsigned int i; float f; } v;
    v.i = u16 << 16;
    return v.f;
}
__device__ __forceinline__ unsigned short f2b(float f) {
    unsigned int i = __float_as_uint(f);
    unsigned int r = (i + 0x7FFFu + ((i >> 16) & 1u)) >> 16;  // RNE
    return (unsigned short)r;
}

#define N_WORD  50000
#define N_TOPIC 2000
#define N_DOC   50000
#define E_MAX   500000
#define CHAIN_END 0xFFFFFFFFu

// ---------------------------------------------------------------
// Input-dtype detection: flag=1 -> bf16 inputs, 0 -> f32 inputs.
// ---------------------------------------------------------------
__global__ void detect_kernel(const unsigned int* __restrict__ feat_u32,
                              unsigned int* __restrict__ flag)
{
    int cnt = 0;
    for (int i = 0; i < 256; ++i) {
        unsigned int u = feat_u32[i];
        int e = (u >> 7) & 0xFF;
        if (e >= 110 && e <= 140) ++cnt;
    }
    *flag = (cnt > 128) ? 1u : 0u;
}

// ---------------------------------------------------------------
// Weight swizzle -> B-fragment order for mfma_f32_16x16x32_bf16.
// ---------------------------------------------------------------
__global__ __launch_bounds__(256) void swizzle_kernel(
    const void* __restrict__ W0, const void* __restrict__ W1,
    const void* __restrict__ W2, const void* __restrict__ W3,
    const void* __restrict__ W4,
    const void* __restrict__ b0, const void* __restrict__ b1,
    const void* __restrict__ b2, const void* __restrict__ b3,
    const void* __restrict__ b4,
    short8* __restrict__ D0, short8* __restrict__ D1,
    short8* __restrict__ D2, short8* __restrict__ D3,
    short8* __restrict__ D4,
    unsigned short* __restrict__ bias_out,
    const unsigned int* __restrict__ flag_p)
{
    const int w = blockIdx.y;
    const void* W; const void* bs; short8* D; int S;
    switch (w) {
        case 0: W = W0; bs = b0; D = D0; S = 8; break;
        case 1: W = W1; bs = b1; D = D1; S = 8; break;
        case 2: W = W2; bs = b2; D = D2; S = 8; break;
        case 3: W = W3; bs = b3; D = D3; S = 4; break;
        default: W = W4; bs = b4; D = D4; S = 4; break;
    }
    const int n_entries = S * 8 * 64;
    const int mode = (int)*flag_p;
    for (int e = blockIdx.x * 256 + threadIdx.x; e < n_entries; e += 8 * 256) {
        const int lane = e & 63, t = (e >> 6) & 7, s = e >> 9;
        const int q = lane >> 4, n = t * 16 + (lane & 15);
        short8 val;
#pragma unroll
        for (int j = 0; j < 8; ++j) {
            const int k = s * 32 + q * 8 + j;
            unsigned short hv = mode ? ((const unsigned short*)W)[k * 128 + n]
                                     : f2b(((const float*)W)[k * 128 + n]);
            val[j] = (short)hv;
        }
        D[e] = val;
    }
    if (blockIdx.x == 0 && threadIdx.x < 128) {
        bias_out[w * 128 + threadIdx.x] =
            mode ? ((const unsigned short*)bs)[threadIdx.x]
                 : f2b(((const float*)bs)[threadIdx.x]);
    }
}

// ---------------------------------------------------------------
// MFMA GEMM body: NP projections of one 16-row A strip.
// ---------------------------------------------------------------
template <int S, int NP>
__device__ __forceinline__ void gemm_body(
    const void* feat_, int n_rows, int bx,
    const short8* Ba, const short8* Bb, const short8* Bc,
    const unsigned short* bias_all, int ba, int bb, int bc,
    unsigned short* Oa, unsigned short* Ob, unsigned short* Oc,
    int mode_bf16)
{
    const int lane = threadIdx.x & 63;
    const int wave = threadIdx.x >> 6;
    const int row0 = (bx * 4 + wave) * 16;
    if (row0 >= n_rows) return;
    const int m = lane & 15, q = lane >> 4;
    const int K = S * 32;

    short8 a[S];
    if (mode_bf16) {
        const short8* arow = (const short8*)((const unsigned short*)feat_ + (size_t)(row0 + m) * K);
#pragma unroll
        for (int s = 0; s < S; ++s) a[s] = arow[s * 4 + q];
    } else {
        const float* arow = (const float*)feat_ + (size_t)(row0 + m) * K;
#pragma unroll
        for (int s = 0; s < S; ++s) {
            const float4 f0 = ((const float4*)arow)[s * 8 + q * 2];
            const float4 f1 = ((const float4*)arow)[s * 8 + q * 2 + 1];
            short8 t;
            t[0] = (short)f2b(f0.x); t[1] = (short)f2b(f0.y);
            t[2] = (short)f2b(f0.z); t[3] = (short)f2b(f0.w);
            t[4] = (short)f2b(f1.x); t[5] = (short)f2b(f1.y);
            t[6] = (short)f2b(f1.z); t[7] = (short)f2b(f1.w);
            a[s] = t;
        }
    }

#pragma unroll
    for (int p = 0; p < NP; ++p) {
        const short8* B = (p == 0) ? Ba : ((p == 1) ? Bb : Bc);
        const unsigned short* bias = bias_all + ((p == 0) ? ba : ((p == 1) ? bb : bc)) * 128;
        unsigned short* O = (p == 0) ? Oa : ((p == 1) ? Ob : Oc);

        floatx4 acc[8];
#pragma unroll
        for (int t = 0; t < 8; ++t) { acc[t][0] = 0.f; acc[t][1] = 0.f; acc[t][2] = 0.f; acc[t][3] = 0.f; }

#pragma unroll
        for (int s = 0; s < S; ++s) {
#pragma unroll
            for (int t = 0; t < 8; ++t) {
                short8 b = B[(s * 8 + t) * 64 + lane];
                acc[t] = __builtin_amdgcn_mfma_f32_16x16x32_bf16(a[s], b, acc[t], 0, 0, 0);
            }
        }

#pragma unroll
        for (int t = 0; t < 8; ++t) {
            const float bb_ = b2f((unsigned int)bias[t * 16 + m]);
#pragma unroll
            for (int r = 0; r < 4; ++r) {
                const int row = row0 + q * 4 + r;
                O[(size_t)row * 128 + t * 16 + m] = f2b(acc[t][r] + bb_);
            }
        }
    }
}

__global__ __launch_bounds__(256) void gemm_all_kernel(
    const void* __restrict__ feat_word, const void* __restrict__ feat_topic,
    const short8* __restrict__ Bww, const short8* __restrict__ Bwt,
    const short8* __restrict__ Bwd, const short8* __restrict__ Btt,
    const short8* __restrict__ Btd,
    const unsigned short* __restrict__ bias_all,
    unsigned short* __restrict__ Wh_ww, unsigned short* __restrict__ Wh_wt,
    unsigned short* __restrict__ Wh_wd, unsigned short* __restrict__ Wh_tt,
    unsigned short* __restrict__ Wh_td,
    const unsigned int* __restrict__ flag_p)
{
    const int mode = (int)*flag_p;
    if (blockIdx.x < 782) {
        gemm_body<8, 3>(feat_word, N_WORD, blockIdx.x, Bww, Bwt, Bwd,
                        bias_all, 0, 1, 2, Wh_ww, Wh_wt, Wh_wd, mode);
    } else {
        gemm_body<4, 2>(feat_topic, N_TOPIC, blockIdx.x - 782, Btt, Btd,
                        (const short8*)nullptr, bias_all, 4, 3, 0,
                        Wh_tt, Wh_td, (unsigned short*)nullptr, mode);
    }
}

// ---------------------------------------------------------------
// Linked-list build (replaces hist+scan+build): per edge i,
//   slot = dst*H + (i & (H-1));  old = atomicExch(&head[slot], i);
//   ent[i] = (old << 32) | (w_bf16 << 16) | src
// ent writes are COALESCED (indexed by i); only the 4B atomicExch is
// random, on a 664KB head region. H=4 sub-chains for topic dsts
// (avg degree 150-200), H=1 for word/doc dsts (avg degree 10).
// ---------------------------------------------------------------
__global__ void link5_kernel(
    const int* s0, const int* d0, const void* w0, int n0, unsigned int* h0, unsigned long long* e0,
    const int* s1, const int* d1, const void* w1, int n1, unsigned int* h1, unsigned long long* e1,
    const int* s2, const int* d2, const void* w2, int n2, unsigned int* h2, unsigned long long* e2,
    const int* s3, const int* d3, const void* w3, int n3, unsigned int* h3, unsigned long long* e3,
    const int* s4, const int* d4, const void* w4, int n4, unsigned int* h4, unsigned long long* e4,
    const unsigned int* __restrict__ flag_p)
{
    const int* src; const int* dst; const void* w_; int n;
    unsigned int* head; unsigned long long* ent; int H;
    switch (blockIdx.y) {
        case 0: src = s0; dst = d0; w_ = w0; n = n0; head = h0; ent = e0; H = 1; break;
        case 1: src = s1; dst = d1; w_ = w1; n = n1; head = h1; ent = e1; H = 4; break;
        case 2: src = s2; dst = d2; w_ = w2; n = n2; head = h2; ent = e2; H = 4; break;
        case 3: src = s3; dst = d3; w_ = w3; n = n3; head = h3; ent = e3; H = 1; break;
        default: src = s4; dst = d4; w_ = w4; n = n4; head = h4; ent = e4; H = 1; break;
    }
    int i = blockIdx.x * 256 + threadIdx.x;
    if (i >= n) return;
    const int d = dst[i];
    const unsigned int slot = (unsigned int)d * H + ((unsigned int)i & (H - 1));
    const unsigned int old = atomicExch(&head[slot], (unsigned int)i);
    const unsigned short w16 = (*flag_p) ? ((const unsigned short*)w_)[i]
                                         : f2b(((const float*)w_)[i]);
    ent[i] = ((unsigned long long)old << 32)
           | ((unsigned long long)w16 << 16)
           | (unsigned long long)(unsigned int)src[i];
}

// ---------------------------------------------------------------
// Chain walk: 16 lanes cover 128 dims (8/lane, uint4 row loads).
// ---------------------------------------------------------------
__device__ __forceinline__ void chain8(
    const unsigned long long* __restrict__ ent,
    const unsigned short* __restrict__ Wh,
    unsigned int e, int sl, float a[8], float& cnt)
{
    while (e != CHAIN_END) {
        const unsigned long long v = ent[e];
        const unsigned int lo = (unsigned int)v;
        e = (unsigned int)(v >> 32);
        const float w = b2f(lo >> 16);
        const uint4 u = ((const uint4*)(Wh + (size_t)(lo & 0xffffu) * 128))[sl];
        a[0] += b2f(u.x & 0xffffu) * w; a[1] += b2f(u.x >> 16) * w;
        a[2] += b2f(u.y & 0xffffu) * w; a[3] += b2f(u.y >> 16) * w;
        a[4] += b2f(u.z & 0xffffu) * w; a[5] += b2f(u.z >> 16) * w;
        a[6] += b2f(u.w & 0xffffu) * w; a[7] += b2f(u.w >> 16) * w;
        cnt += 1.0f;
    }
}

__device__ __forceinline__ void write8(
    void* out, size_t off_elems, int node, int sl, const float r[8], int mode)
{
    if (mode) {
        uint4 o;
        o.x = (unsigned int)f2b(r[0]) | ((unsigned int)f2b(r[1]) << 16);
        o.y = (unsigned int)f2b(r[2]) | ((unsigned int)f2b(r[3]) << 16);
        o.z = (unsigned int)f2b(r[4]) | ((unsigned int)f2b(r[5]) << 16);
        o.w = (unsigned int)f2b(r[6]) | ((unsigned int)f2b(r[7]) << 16);
        *(uint4*)((unsigned short*)out + off_elems + (size_t)node * 128 + sl * 8) = o;
    } else {
        float* p = (float*)out + off_elems + (size_t)node * 128 + sl * 8;
        ((float4*)p)[0] = make_float4(r[0], r[1], r[2], r[3]);
        ((float4*)p)[1] = make_float4(r[4], r[5], r[6], r[7]);
    }
}

// ---------------------------------------------------------------
// Gather doc+topic. Blocks [0,500): topic (1 node/wave, the wave's four
// 16-lane groups walk the node's 4 sub-chains in parallel; shfl-reduce).
// Blocks [500,3625): doc (4 nodes/wave, H=1 chains).
// Reads Wh_wd staged in d_out's word region (disjoint from topic/doc out).
// ---------------------------------------------------------------
__global__ __launch_bounds__(256) void gather_dt_kernel(
    const unsigned int* __restrict__ h_wt, const unsigned long long* __restrict__ e_wt,
    const unsigned short* __restrict__ Wh_wt,
    const unsigned int* __restrict__ h_tt, const unsigned long long* __restrict__ e_tt,
    const unsigned short* __restrict__ Wh_tt,
    const unsigned int* __restrict__ h_wd, const unsigned long long* __restrict__ e_wd,
    const unsigned short* __restrict__ Wh_wd,
    const unsigned int* __restrict__ h_td, const unsigned long long* __restrict__ e_td,
    const unsigned short* __restrict__ Wh_td,
    void* __restrict__ out,
    const unsigned int* __restrict__ flag_p)
{
    const int mode = (int)*flag_p;
    const int sl = threadIdx.x & 15;

    if (blockIdx.x < 500) {                      // ---- topic ----
        const int wave = threadIdx.x >> 6;
        const int grp  = (threadIdx.x >> 4) & 3; // sub-chain id
        const int node = blockIdx.x * 4 + wave;
        float r[8] = {0, 0, 0, 0, 0, 0, 0, 0};
        {
            float a[8] = {0, 0, 0, 0, 0, 0, 0, 0}; float cnt = 0.f;
            chain8(e_wt, Wh_wt, h_wt[node * 4 + grp], sl, a, cnt);
#pragma unroll
            for (int j = 0; j < 8; ++j) { a[j] += __shfl_xor(a[j], 16); a[j] += __shfl_xor(a[j], 32); }
            cnt += __shfl_xor(cnt, 16); cnt += __shfl_xor(cnt, 32);
            const float inv = (cnt > 0.f) ? 1.f / cnt : 0.f;
#pragma unroll
            for (int j = 0; j < 8; ++j) r[j] += a[j] * inv;
        }
        {
            float a[8] = {0, 0, 0, 0, 0, 0, 0, 0}; float cnt = 0.f;
            chain8(e_tt, Wh_tt, h_tt[node * 4 + grp], sl, a, cnt);
#pragma unroll
            for (int j = 0; j < 8; ++j) { a[j] += __shfl_xor(a[j], 16); a[j] += __shfl_xor(a[j], 32); }
            cnt += __shfl_xor(cnt, 16); cnt += __shfl_xor(cnt, 32);
            const float inv = (cnt > 0.f) ? 1.f / cnt : 0.f;
#pragma unroll
            for (int j = 0; j < 8; ++j) r[j] += a[j] * inv;
        }
        if (grp == 0) write8(out, (size_t)6400000, node, sl, r, mode);
    } else {                                     // ---- doc ----
        const int sub = threadIdx.x >> 4;        // 0..15
        const int node = (blockIdx.x - 500) * 16 + sub;
        float r[8] = {0, 0, 0, 0, 0, 0, 0, 0};
        {
            float a[8] = {0, 0, 0, 0, 0, 0, 0, 0}; float cnt = 0.f;
            chain8(e_wd, Wh_wd, h_wd[node], sl, a, cnt);
            const float inv = (cnt > 0.f) ? 1.f / cnt : 0.f;
#pragma unroll
            for (int j = 0; j < 8; ++j) r[j] += a[j] * inv;
        }
        {
            float a[8] = {0, 0, 0, 0, 0, 0, 0, 0}; float cnt = 0.f;
            chain8(e_td, Wh_td, h_td[node], sl, a, cnt);
            const float inv = (cnt > 0.f) ? 1.f / cnt : 0.f;
#pragma unroll
            for (int j = 0; j < 8; ++j) r[j] += a[j] * inv;
        }
        write8(out, (size_t)6656000, node, sl, r, mode);
    }
}

// ---------------------------------------------------------------
// Gather word (runs last; overwrites the Wh_wd staging region in d_out).
// ---------------------------------------------------------------
__global__ __launch_bounds__(256) void gather_w_kernel(
    const unsigned int* __restrict__ h_ww, const unsigned long long* __restrict__ e_ww,
    const unsigned short* __restrict__ Wh_ww,
    void* __restrict__ out,
    const unsigned int* __restrict__ flag_p)
{
    const int mode = (int)*flag_p;
    const int sl = threadIdx.x & 15;
    const int sub = threadIdx.x >> 4;
    const int node = blockIdx.x * 16 + sub;
    float a[8] = {0, 0, 0, 0, 0, 0, 0, 0}; float cnt = 0.f;
    chain8(e_ww, Wh_ww, h_ww[node], sl, a, cnt);
    const float inv = (cnt > 0.f) ? 1.f / cnt : 0.f;
#pragma unroll
    for (int j = 0; j < 8; ++j) a[j] *= inv;
    write8(out, 0, node, sl, a, mode);
}

// ---------------------------------------------------------------
extern "C" void kernel_launch(void* const* d_in, const int* in_sizes, int n_in,
                              void* d_out, int out_size, void* d_ws, size_t ws_size,
                              hipStream_t stream)
{
    const void* feat_word  = d_in[0];
    const void* feat_topic = d_in[1];
    const int* ww_src = (const int*)d_in[2];
    const int* ww_dst = (const int*)d_in[3];
    const void* ww_w = d_in[4];
    const int* wt_src = (const int*)d_in[5];
    const int* wt_dst = (const int*)d_in[6];
    const void* wt_w = d_in[7];
    const int* wd_src = (const int*)d_in[8];
    const int* wd_dst = (const int*)d_in[9];
    const void* wd_w = d_in[10];
    const int* td_src = (const int*)d_in[11];
    const int* td_dst = (const int*)d_in[12];
    const void* td_w = d_in[13];
    const int* tt_src = (const int*)d_in[14];
    const int* tt_dst = (const int*)d_in[15];
    const void* tt_w = d_in[16];
    const void* W_ww = d_in[17];
    const void* b_ww = d_in[18];
    const void* W_wt = d_in[19];
    const void* b_wt = d_in[20];
    const void* W_wd = d_in[21];
    const void* b_wd = d_in[22];
    const void* W_td = d_in[23];
    const void* b_td = d_in[24];
    const void* W_tt = d_in[25];
    const void* b_tt = d_in[26];

    const int E_ww = in_sizes[2];
    const int E_wt = in_sizes[5];
    const int E_wd = in_sizes[8];
    const int E_td = in_sizes[11];
    const int E_tt = in_sizes[14];

    // ---------------- workspace layout (~47 MB) ----------------
    char* ws = (char*)d_ws;
    unsigned int* flag = (unsigned int*)ws;                      // 4 B
    unsigned int* head_base = (unsigned int*)(ws + 4);           // 166,000 u32
    unsigned int* h_ww = head_base;                              // 50,000 (H=1)
    unsigned int* h_wt = h_ww + 50000;                           //  8,000 (H=4)
    unsigned int* h_tt = h_wt + 8000;                            //  8,000 (H=4)
    unsigned int* h_wd = h_tt + 8000;                            // 50,000
    unsigned int* h_td = h_wd + 50000;                           // 50,000
    size_t off = 4 + (size_t)166000 * 4;
    off = (off + 15) & ~(size_t)15;
    short8* Bsw_ww = (short8*)(ws + off); off += 65536;
    short8* Bsw_wt = (short8*)(ws + off); off += 65536;
    short8* Bsw_wd = (short8*)(ws + off); off += 65536;
    short8* Bsw_td = (short8*)(ws + off); off += 32768;
    short8* Bsw_tt = (short8*)(ws + off); off += 32768;
    unsigned short* bias_all = (unsigned short*)(ws + off); off += 5 * 128 * 2;
    off = (off + 15) & ~(size_t)15;
    unsigned short* Wh_ww = (unsigned short*)(ws + off); off += (size_t)N_WORD * 128 * 2;
    unsigned short* Wh_wt = (unsigned short*)(ws + off); off += (size_t)N_WORD * 128 * 2;
    unsigned short* Wh_tt = (unsigned short*)(ws + off); off += (size_t)N_TOPIC * 128 * 2;
    unsigned short* Wh_td = (unsigned short*)(ws + off); off += (size_t)N_TOPIC * 128 * 2;
    off = (off + 7) & ~(size_t)7;
    unsigned long long* e_ww = (unsigned long long*)(ws + off); off += (size_t)E_MAX * 8;
    unsigned long long* e_wt = (unsigned long long*)(ws + off); off += (size_t)E_MAX * 8;
    unsigned long long* e_tt = (unsigned long long*)(ws + off); off += (size_t)E_MAX * 8;
    unsigned long long* e_wd = (unsigned long long*)(ws + off); off += (size_t)E_MAX * 8;
    unsigned long long* e_td = (unsigned long long*)(ws + off); off += (size_t)E_MAX * 8;

    // Wh_wd staged in d_out's word region (12.8 MB); gather_dt reads it,
    // gather_w overwrites it last.
    unsigned short* Wh_wd = (unsigned short*)d_out;

    detect_kernel<<<1, 1, 0, stream>>>((const unsigned int*)feat_word, flag);
    hipMemsetAsync(head_base, 0xFF, (size_t)166000 * 4, stream);   // all chains end

    swizzle_kernel<<<dim3(8, 5), 256, 0, stream>>>(
        W_ww, W_wt, W_wd, W_td, W_tt, b_ww, b_wt, b_wd, b_td, b_tt,
        Bsw_ww, Bsw_wt, Bsw_wd, Bsw_td, Bsw_tt, bias_all, flag);

    link5_kernel<<<dim3((E_MAX + 255) / 256, 5), 256, 0, stream>>>(
        ww_src, ww_dst, ww_w, E_ww, h_ww, e_ww,
        wt_src, wt_dst, wt_w, E_wt, h_wt, e_wt,
        tt_src, tt_dst, tt_w, E_tt, h_tt, e_tt,
        wd_src, wd_dst, wd_w, E_wd, h_wd, e_wd,
        td_src, td_dst, td_w, E_td, h_td, e_td, flag);

    gemm_all_kernel<<<782 + 32, 256, 0, stream>>>(
        feat_word, feat_topic, Bsw_ww, Bsw_wt, Bsw_wd, Bsw_tt, Bsw_td,
        bias_all, Wh_ww, Wh_wt, Wh_wd, Wh_tt, Wh_td, flag);

    gather_dt_kernel<<<500 + 3125, 256, 0, stream>>>(
        h_wt, e_wt, Wh_wt, h_tt, e_tt, Wh_tt,
        h_wd, e_wd, Wh_wd, h_td, e_td, Wh_td, d_out, flag);

    gather_w_kernel<<<3125, 256, 0, stream>>>(
        h_ww, e_ww, Wh_ww, d_out, flag);
}

// Round 9
// 431.985 us; speedup vs baseline: 5.6755x; 1.1254x over previous
//
#include <hip/hip_runtime.h>

typedef short short8 __attribute__((ext_vector_type(8)));
typedef float floatx4 __attribute__((ext_vector_type(4)));

// ---------- bf16 helpers (raw ushort representation) ----------
__device__ __forceinline__ float b2f(unsigned int u16) {
    union { unsigned int i; float f; } v;
    v.i = u16 << 16;
    return v.f;
}
__device__ __forceinline__ unsigned short f2b(float f) {
    unsigned int i = __float_as_uint(f);
    unsigned int r = (i + 0x7FFFu + ((i >> 16) & 1u)) >> 16;  // RNE
    return (unsigned short)r;
}

#define N_WORD  50000
#define N_TOPIC 2000
#define N_DOC   50000
#define E_MAX   500000
#define CHAIN_END 0xFFFFFFFFu

// ---------------------------------------------------------------
// Input-dtype detection: flag=1 -> bf16 inputs, 0 -> f32 inputs.
// ---------------------------------------------------------------
__global__ void detect_kernel(const unsigned int* __restrict__ feat_u32,
                              unsigned int* __restrict__ flag)
{
    int cnt = 0;
    for (int i = 0; i < 256; ++i) {
        unsigned int u = feat_u32[i];
        int e = (u >> 7) & 0xFF;
        if (e >= 110 && e <= 140) ++cnt;
    }
    *flag = (cnt > 128) ? 1u : 0u;
}

// ---------------------------------------------------------------
// Weight swizzle -> B-fragment order for mfma_f32_16x16x32_bf16.
// ---------------------------------------------------------------
__global__ __launch_bounds__(256) void swizzle_kernel(
    const void* __restrict__ W0, const void* __restrict__ W1,
    const void* __restrict__ W2, const void* __restrict__ W3,
    const void* __restrict__ W4,
    const void* __restrict__ b0, const void* __restrict__ b1,
    const void* __restrict__ b2, const void* __restrict__ b3,
    const void* __restrict__ b4,
    short8* __restrict__ D0, short8* __restrict__ D1,
    short8* __restrict__ D2, short8* __restrict__ D3,
    short8* __restrict__ D4,
    unsigned short* __restrict__ bias_out,
    const unsigned int* __restrict__ flag_p)
{
    const int w = blockIdx.y;
    const void* W; const void* bs; short8* D; int S;
    switch (w) {
        case 0: W = W0; bs = b0; D = D0; S = 8; break;
        case 1: W = W1; bs = b1; D = D1; S = 8; break;
        case 2: W = W2; bs = b2; D = D2; S = 8; break;
        case 3: W = W3; bs = b3; D = D3; S = 4; break;
        default: W = W4; bs = b4; D = D4; S = 4; break;
    }
    const int n_entries = S * 8 * 64;
    const int mode = (int)*flag_p;
    for (int e = blockIdx.x * 256 + threadIdx.x; e < n_entries; e += 8 * 256) {
        const int lane = e & 63, t = (e >> 6) & 7, s = e >> 9;
        const int q = lane >> 4, n = t * 16 + (lane & 15);
        short8 val;
#pragma unroll
        for (int j = 0; j < 8; ++j) {
            const int k = s * 32 + q * 8 + j;
            unsigned short hv = mode ? ((const unsigned short*)W)[k * 128 + n]
                                     : f2b(((const float*)W)[k * 128 + n]);
            val[j] = (short)hv;
        }
        D[e] = val;
    }
    if (blockIdx.x == 0 && threadIdx.x < 128) {
        bias_out[w * 128 + threadIdx.x] =
            mode ? ((const unsigned short*)bs)[threadIdx.x]
                 : f2b(((const float*)bs)[threadIdx.x]);
    }
}

// ---------------------------------------------------------------
// MFMA GEMM body with LDS-staged B. NO early return (all waves must hit
// the barriers); OOB rows clamped on load, guarded on store.
// Per phase: block stages the full B (S*8*64 short8 = 32/64 KB) into
// LDS, syncs, 4 waves stream conflict-free ds_read_b128 + MFMA.
// ---------------------------------------------------------------
template <int S, int NP>
__device__ __forceinline__ void gemm_body_lds(
    short8* __restrict__ Blds,
    const void* feat_, int n_rows, int bx,
    const short8* Ba, const short8* Bb, const short8* Bc,
    const unsigned short* bias_all, int ba, int bb, int bc,
    unsigned short* Oa, unsigned short* Ob, unsigned short* Oc,
    int mode_bf16)
{
    const int tid = threadIdx.x;
    const int lane = tid & 63;
    const int wave = tid >> 6;
    const int row0 = (bx * 4 + wave) * 16;
    const int m = lane & 15, q = lane >> 4;
    const int K = S * 32;
    int arow_idx = row0 + m;
    if (arow_idx >= n_rows) arow_idx = n_rows - 1;   // clamp (store guarded)

    short8 a[S];
    if (mode_bf16) {
        const short8* arow = (const short8*)((const unsigned short*)feat_ + (size_t)arow_idx * K);
#pragma unroll
        for (int s = 0; s < S; ++s) a[s] = arow[s * 4 + q];
    } else {
        const float* arow = (const float*)feat_ + (size_t)arow_idx * K;
#pragma unroll
        for (int s = 0; s < S; ++s) {
            const float4 f0 = ((const float4*)arow)[s * 8 + q * 2];
            const float4 f1 = ((const float4*)arow)[s * 8 + q * 2 + 1];
            short8 t;
            t[0] = (short)f2b(f0.x); t[1] = (short)f2b(f0.y);
            t[2] = (short)f2b(f0.z); t[3] = (short)f2b(f0.w);
            t[4] = (short)f2b(f1.x); t[5] = (short)f2b(f1.y);
            t[6] = (short)f2b(f1.z); t[7] = (short)f2b(f1.w);
            a[s] = t;
        }
    }

    const int n_ent = S * 8 * 64;
#pragma unroll
    for (int p = 0; p < NP; ++p) {
        const short8* B = (p == 0) ? Ba : ((p == 1) ? Bb : Bc);
        const unsigned short* bias = bias_all + ((p == 0) ? ba : ((p == 1) ? bb : bc)) * 128;
        unsigned short* O = (p == 0) ? Oa : ((p == 1) ? Ob : Oc);

        // stage B into LDS (coalesced 16 B/lane)
        for (int i = tid; i < n_ent; i += 256) Blds[i] = B[i];
        __syncthreads();

        floatx4 acc[8];
#pragma unroll
        for (int t = 0; t < 8; ++t) { acc[t][0] = 0.f; acc[t][1] = 0.f; acc[t][2] = 0.f; acc[t][3] = 0.f; }

#pragma unroll
        for (int s = 0; s < S; ++s) {
#pragma unroll
            for (int t = 0; t < 8; ++t) {
                short8 b = Blds[(s * 8 + t) * 64 + lane];
                acc[t] = __builtin_amdgcn_mfma_f32_16x16x32_bf16(a[s], b, acc[t], 0, 0, 0);
            }
        }
        __syncthreads();   // all LDS reads done before next phase overwrites

#pragma unroll
        for (int t = 0; t < 8; ++t) {
            const float bb_ = b2f((unsigned int)bias[t * 16 + m]);
#pragma unroll
            for (int r = 0; r < 4; ++r) {
                const int row = row0 + q * 4 + r;
                if (row < n_rows)
                    O[(size_t)row * 128 + t * 16 + m] = f2b(acc[t][r] + bb_);
            }
        }
    }
}

__global__ __launch_bounds__(256) void gemm_all_kernel(
    const void* __restrict__ feat_word, const void* __restrict__ feat_topic,
    const short8* __restrict__ Bww, const short8* __restrict__ Bwt,
    const short8* __restrict__ Bwd, const short8* __restrict__ Btt,
    const short8* __restrict__ Btd,
    const unsigned short* __restrict__ bias_all,
    unsigned short* __restrict__ Wh_ww, unsigned short* __restrict__ Wh_wt,
    unsigned short* __restrict__ Wh_wd, unsigned short* __restrict__ Wh_tt,
    unsigned short* __restrict__ Wh_td,
    const unsigned int* __restrict__ flag_p)
{
    __shared__ short8 Blds[4096];   // 64 KB
    const int mode = (int)*flag_p;
    if (blockIdx.x < 782) {
        gemm_body_lds<8, 3>(Blds, feat_word, N_WORD, blockIdx.x, Bww, Bwt, Bwd,
                            bias_all, 0, 1, 2, Wh_ww, Wh_wt, Wh_wd, mode);
    } else {
        gemm_body_lds<4, 2>(Blds, feat_topic, N_TOPIC, blockIdx.x - 782, Btt, Btd,
                            (const short8*)nullptr, bias_all, 4, 3, 0,
                            Wh_tt, Wh_td, (unsigned short*)nullptr, mode);
    }
}

// ---------------------------------------------------------------
// Linked-list build: per edge i,
//   slot = dst*H + (i & (H-1));  old = atomicExch(&head[slot], i);
//   ent[i] = (old << 32) | (w_bf16 << 16) | src
// ent writes are coalesced; only the 4B atomicExch is random (664 KB).
// H=4 sub-chains for topic dsts, H=1 for word/doc dsts.
// ---------------------------------------------------------------
__global__ void link5_kernel(
    const int* s0, const int* d0, const void* w0, int n0, unsigned int* h0, unsigned long long* e0,
    const int* s1, const int* d1, const void* w1, int n1, unsigned int* h1, unsigned long long* e1,
    const int* s2, const int* d2, const void* w2, int n2, unsigned int* h2, unsigned long long* e2,
    const int* s3, const int* d3, const void* w3, int n3, unsigned int* h3, unsigned long long* e3,
    const int* s4, const int* d4, const void* w4, int n4, unsigned int* h4, unsigned long long* e4,
    const unsigned int* __restrict__ flag_p)
{
    const int* src; const int* dst; const void* w_; int n;
    unsigned int* head; unsigned long long* ent; int H;
    switch (blockIdx.y) {
        case 0: src = s0; dst = d0; w_ = w0; n = n0; head = h0; ent = e0; H = 1; break;
        case 1: src = s1; dst = d1; w_ = w1; n = n1; head = h1; ent = e1; H = 4; break;
        case 2: src = s2; dst = d2; w_ = w2; n = n2; head = h2; ent = e2; H = 4; break;
        case 3: src = s3; dst = d3; w_ = w3; n = n3; head = h3; ent = e3; H = 1; break;
        default: src = s4; dst = d4; w_ = w4; n = n4; head = h4; ent = e4; H = 1; break;
    }
    int i = blockIdx.x * 256 + threadIdx.x;
    if (i >= n) return;
    const int d = dst[i];
    const unsigned int slot = (unsigned int)d * H + ((unsigned int)i & (H - 1));
    const unsigned int old = atomicExch(&head[slot], (unsigned int)i);
    const unsigned short w16 = (*flag_p) ? ((const unsigned short*)w_)[i]
                                         : f2b(((const float*)w_)[i]);
    ent[i] = ((unsigned long long)old << 32)
           | ((unsigned long long)w16 << 16)
           | (unsigned long long)(unsigned int)src[i];
}

// ---------------------------------------------------------------
// Chain walk: 16 lanes cover 128 dims (8/lane, uint4 row loads).
// ---------------------------------------------------------------
__device__ __forceinline__ void chain8(
    const unsigned long long* __restrict__ ent,
    const unsigned short* __restrict__ Wh,
    unsigned int e, int sl, float a[8], float& cnt)
{
    while (e != CHAIN_END) {
        const unsigned long long v = ent[e];
        const unsigned int lo = (unsigned int)v;
        e = (unsigned int)(v >> 32);
        const float w = b2f(lo >> 16);
        const uint4 u = ((const uint4*)(Wh + (size_t)(lo & 0xffffu) * 128))[sl];
        a[0] += b2f(u.x & 0xffffu) * w; a[1] += b2f(u.x >> 16) * w;
        a[2] += b2f(u.y & 0xffffu) * w; a[3] += b2f(u.y >> 16) * w;
        a[4] += b2f(u.z & 0xffffu) * w; a[5] += b2f(u.z >> 16) * w;
        a[6] += b2f(u.w & 0xffffu) * w; a[7] += b2f(u.w >> 16) * w;
        cnt += 1.0f;
    }
}

__device__ __forceinline__ void write8(
    void* out, size_t off_elems, int node, int sl, const float r[8], int mode)
{
    if (mode) {
        uint4 o;
        o.x = (unsigned int)f2b(r[0]) | ((unsigned int)f2b(r[1]) << 16);
        o.y = (unsigned int)f2b(r[2]) | ((unsigned int)f2b(r[3]) << 16);
        o.z = (unsigned int)f2b(r[4]) | ((unsigned int)f2b(r[5]) << 16);
        o.w = (unsigned int)f2b(r[6]) | ((unsigned int)f2b(r[7]) << 16);
        *(uint4*)((unsigned short*)out + off_elems + (size_t)node * 128 + sl * 8) = o;
    } else {
        float* p = (float*)out + off_elems + (size_t)node * 128 + sl * 8;
        ((float4*)p)[0] = make_float4(r[0], r[1], r[2], r[3]);
        ((float4*)p)[1] = make_float4(r[4], r[5], r[6], r[7]);
    }
}

// ---------------------------------------------------------------
// Gather doc+topic. Blocks [0,500): topic (1 node/wave, 4 sub-chains
// in parallel, shfl-reduce). Blocks [500,3625): doc (H=1 chains).
// Reads Wh_wd staged in d_out's word region.
// ---------------------------------------------------------------
__global__ __launch_bounds__(256) void gather_dt_kernel(
    const unsigned int* __restrict__ h_wt, const unsigned long long* __restrict__ e_wt,
    const unsigned short* __restrict__ Wh_wt,
    const unsigned int* __restrict__ h_tt, const unsigned long long* __restrict__ e_tt,
    const unsigned short* __restrict__ Wh_tt,
    const unsigned int* __restrict__ h_wd, const unsigned long long* __restrict__ e_wd,
    const unsigned short* __restrict__ Wh_wd,
    const unsigned int* __restrict__ h_td, const unsigned long long* __restrict__ e_td,
    const unsigned short* __restrict__ Wh_td,
    void* __restrict__ out,
    const unsigned int* __restrict__ flag_p)
{
    const int mode = (int)*flag_p;
    const int sl = threadIdx.x & 15;

    if (blockIdx.x < 500) {                      // ---- topic ----
        const int wave = threadIdx.x >> 6;
        const int grp  = (threadIdx.x >> 4) & 3;
        const int node = blockIdx.x * 4 + wave;
        float r[8] = {0, 0, 0, 0, 0, 0, 0, 0};
        {
            float a[8] = {0, 0, 0, 0, 0, 0, 0, 0}; float cnt = 0.f;
            chain8(e_wt, Wh_wt, h_wt[node * 4 + grp], sl, a, cnt);
#pragma unroll
            for (int j = 0; j < 8; ++j) { a[j] += __shfl_xor(a[j], 16); a[j] += __shfl_xor(a[j], 32); }
            cnt += __shfl_xor(cnt, 16); cnt += __shfl_xor(cnt, 32);
            const float inv = (cnt > 0.f) ? 1.f / cnt : 0.f;
#pragma unroll
            for (int j = 0; j < 8; ++j) r[j] += a[j] * inv;
        }
        {
            float a[8] = {0, 0, 0, 0, 0, 0, 0, 0}; float cnt = 0.f;
            chain8(e_tt, Wh_tt, h_tt[node * 4 + grp], sl, a, cnt);
#pragma unroll
            for (int j = 0; j < 8; ++j) { a[j] += __shfl_xor(a[j], 16); a[j] += __shfl_xor(a[j], 32); }
            cnt += __shfl_xor(cnt, 16); cnt += __shfl_xor(cnt, 32);
            const float inv = (cnt > 0.f) ? 1.f / cnt : 0.f;
#pragma unroll
            for (int j = 0; j < 8; ++j) r[j] += a[j] * inv;
        }
        if (grp == 0) write8(out, (size_t)6400000, node, sl, r, mode);
    } else {                                     // ---- doc ----
        const int sub = threadIdx.x >> 4;
        const int node = (blockIdx.x - 500) * 16 + sub;
        float r[8] = {0, 0, 0, 0, 0, 0, 0, 0};
        {
            float a[8] = {0, 0, 0, 0, 0, 0, 0, 0}; float cnt = 0.f;
            chain8(e_wd, Wh_wd, h_wd[node], sl, a, cnt);
            const float inv = (cnt > 0.f) ? 1.f / cnt : 0.f;
#pragma unroll
            for (int j = 0; j < 8; ++j) r[j] += a[j] * inv;
        }
        {
            float a[8] = {0, 0, 0, 0, 0, 0, 0, 0}; float cnt = 0.f;
            chain8(e_td, Wh_td, h_td[node], sl, a, cnt);
            const float inv = (cnt > 0.f) ? 1.f / cnt : 0.f;
#pragma unroll
            for (int j = 0; j < 8; ++j) r[j] += a[j] * inv;
        }
        write8(out, (size_t)6656000, node, sl, r, mode);
    }
}

// ---------------------------------------------------------------
// Gather word (runs last; overwrites the Wh_wd staging region in d_out).
// ---------------------------------------------------------------
__global__ __launch_bounds__(256) void gather_w_kernel(
    const unsigned int* __restrict__ h_ww, const unsigned long long* __restrict__ e_ww,
    const unsigned short* __restrict__ Wh_ww,
    void* __restrict__ out,
    const unsigned int* __restrict__ flag_p)
{
    const int mode = (int)*flag_p;
    const int sl = threadIdx.x & 15;
    const int sub = threadIdx.x >> 4;
    const int node = blockIdx.x * 16 + sub;
    float a[8] = {0, 0, 0, 0, 0, 0, 0, 0}; float cnt = 0.f;
    chain8(e_ww, Wh_ww, h_ww[node], sl, a, cnt);
    const float inv = (cnt > 0.f) ? 1.f / cnt : 0.f;
#pragma unroll
    for (int j = 0; j < 8; ++j) a[j] *= inv;
    write8(out, 0, node, sl, a, mode);
}

// ---------------------------------------------------------------
extern "C" void kernel_launch(void* const* d_in, const int* in_sizes, int n_in,
                              void* d_out, int out_size, void* d_ws, size_t ws_size,
                              hipStream_t stream)
{
    const void* feat_word  = d_in[0];
    const void* feat_topic = d_in[1];
    const int* ww_src = (const int*)d_in[2];
    const int* ww_dst = (const int*)d_in[3];
    const void* ww_w = d_in[4];
    const int* wt_src = (const int*)d_in[5];
    const int* wt_dst = (const int*)d_in[6];
    const void* wt_w = d_in[7];
    const int* wd_src = (const int*)d_in[8];
    const int* wd_dst = (const int*)d_in[9];
    const void* wd_w = d_in[10];
    const int* td_src = (const int*)d_in[11];
    const int* td_dst = (const int*)d_in[12];
    const void* td_w = d_in[13];
    const int* tt_src = (const int*)d_in[14];
    const int* tt_dst = (const int*)d_in[15];
    const void* tt_w = d_in[16];
    const void* W_ww = d_in[17];
    const void* b_ww = d_in[18];
    const void* W_wt = d_in[19];
    const void* b_wt = d_in[20];
    const void* W_wd = d_in[21];
    const void* b_wd = d_in[22];
    const void* W_td = d_in[23];
    const void* b_td = d_in[24];
    const void* W_tt = d_in[25];
    const void* b_tt = d_in[26];

    const int E_ww = in_sizes[2];
    const int E_wt = in_sizes[5];
    const int E_wd = in_sizes[8];
    const int E_td = in_sizes[11];
    const int E_tt = in_sizes[14];

    // ---------------- workspace layout (~47 MB) ----------------
    char* ws = (char*)d_ws;
    unsigned int* flag = (unsigned int*)ws;
    unsigned int* head_base = (unsigned int*)(ws + 4);
    unsigned int* h_ww = head_base;                              // 50,000 (H=1)
    unsigned int* h_wt = h_ww + 50000;                           //  8,000 (H=4)
    unsigned int* h_tt = h_wt + 8000;                            //  8,000 (H=4)
    unsigned int* h_wd = h_tt + 8000;                            // 50,000
    unsigned int* h_td = h_wd + 50000;                           // 50,000
    size_t off = 4 + (size_t)166000 * 4;
    off = (off + 15) & ~(size_t)15;
    short8* Bsw_ww = (short8*)(ws + off); off += 65536;
    short8* Bsw_wt = (short8*)(ws + off); off += 65536;
    short8* Bsw_wd = (short8*)(ws + off); off += 65536;
    short8* Bsw_td = (short8*)(ws + off); off += 32768;
    short8* Bsw_tt = (short8*)(ws + off); off += 32768;
    unsigned short* bias_all = (unsigned short*)(ws + off); off += 5 * 128 * 2;
    off = (off + 15) & ~(size_t)15;
    unsigned short* Wh_ww = (unsigned short*)(ws + off); off += (size_t)N_WORD * 128 * 2;
    unsigned short* Wh_wt = (unsigned short*)(ws + off); off += (size_t)N_WORD * 128 * 2;
    unsigned short* Wh_tt = (unsigned short*)(ws + off); off += (size_t)N_TOPIC * 128 * 2;
    unsigned short* Wh_td = (unsigned short*)(ws + off); off += (size_t)N_TOPIC * 128 * 2;
    off = (off + 7) & ~(size_t)7;
    unsigned long long* e_ww = (unsigned long long*)(ws + off); off += (size_t)E_MAX * 8;
    unsigned long long* e_wt = (unsigned long long*)(ws + off); off += (size_t)E_MAX * 8;
    unsigned long long* e_tt = (unsigned long long*)(ws + off); off += (size_t)E_MAX * 8;
    unsigned long long* e_wd = (unsigned long long*)(ws + off); off += (size_t)E_MAX * 8;
    unsigned long long* e_td = (unsigned long long*)(ws + off); off += (size_t)E_MAX * 8;

    // Wh_wd staged in d_out's word region (12.8 MB); gather_dt reads it,
    // gather_w overwrites it last.
    unsigned short* Wh_wd = (unsigned short*)d_out;

    detect_kernel<<<1, 1, 0, stream>>>((const unsigned int*)feat_word, flag);
    hipMemsetAsync(head_base, 0xFF, (size_t)166000 * 4, stream);   // chain ends

    swizzle_kernel<<<dim3(8, 5), 256, 0, stream>>>(
        W_ww, W_wt, W_wd, W_td, W_tt, b_ww, b_wt, b_wd, b_td, b_tt,
        Bsw_ww, Bsw_wt, Bsw_wd, Bsw_td, Bsw_tt, bias_all, flag);

    link5_kernel<<<dim3((E_MAX + 255) / 256, 5), 256, 0, stream>>>(
        ww_src, ww_dst, ww_w, E_ww, h_ww, e_ww,
        wt_src, wt_dst, wt_w, E_wt, h_wt, e_wt,
        tt_src, tt_dst, tt_w, E_tt, h_tt, e_tt,
        wd_src, wd_dst, wd_w, E_wd, h_wd, e_wd,
        td_src, td_dst, td_w, E_td, h_td, e_td, flag);

    gemm_all_kernel<<<782 + 32, 256, 0, stream>>>(
        feat_word, feat_topic, Bsw_ww, Bsw_wt, Bsw_wd, Bsw_tt, Bsw_td,
        bias_all, Wh_ww, Wh_wt, Wh_wd, Wh_tt, Wh_td, flag);

    gather_dt_kernel<<<500 + 3125, 256, 0, stream>>>(
        h_wt, e_wt, Wh_wt, h_tt, e_tt, Wh_tt,
        h_wd, e_wd, Wh_wd, h_td, e_td, Wh_td, d_out, flag);

    gather_w_kernel<<<3125, 256, 0, stream>>>(
        h_ww, e_ww, Wh_ww, d_out, flag);
}